// Round 1
// baseline (967.684 us; speedup 1.0000x reference)
//
#include <hip/hip_runtime.h>
#include <math.h>

#define BN 32
#define HN 512
#define WN 512
#define REGION 30
#define UFV 20.0f
#define DFTSHIFT 15.0f
#define TWO_PI 6.2831853071795864769f

typedef float2 cplx;

__device__ __forceinline__ cplx cmul(cplx a, cplx b){
    return make_float2(a.x*b.x - a.y*b.y, a.x*b.y + a.y*b.x);
}
__device__ __forceinline__ cplx cadd(cplx a, cplx b){
    return make_float2(a.x + b.x, a.y + b.y);
}
__device__ __forceinline__ int brev9(int i){ return (int)(__brev((unsigned)i) >> 23); }

// ---- in-LDS 512-point radix-2 DIT FFT, 256 threads, data already bit-reversed ----
__device__ __forceinline__ void fft512_stages(cplx* sm, int tid, float sign){
    #pragma unroll
    for (int st = 1; st <= 9; ++st){
        const int m = 1 << st, half = m >> 1;
        const int j   = tid & (half - 1);
        const int grp = tid >> (st - 1);
        const int i0  = grp * m + j, i1 = i0 + half;
        float sv, cv; sincosf(sign * TWO_PI * (float)j / (float)m, &sv, &cv);
        cplx a = sm[i0];
        cplx t = cmul(make_float2(cv, sv), sm[i1]);
        sm[i0] = make_float2(a.x + t.x, a.y + t.y);
        sm[i1] = make_float2(a.x - t.x, a.y - t.y);
        __syncthreads();
    }
}

// Row-wise forward FFT of both real inputs. grid (BN*HN, 2), block 256.
__global__ void row_fft_fwd(const float* __restrict__ tin, const float* __restrict__ sin_,
                            cplx* __restrict__ ft, cplx* __restrict__ fs){
    const int rid = blockIdx.x;
    const float* in = (blockIdx.y == 0) ? tin : sin_;
    cplx* out       = (blockIdx.y == 0) ? ft  : fs;
    __shared__ cplx sm[WN];
    const int tid = threadIdx.x;
    const float* row = in + (size_t)rid * WN;
    for (int i = tid; i < WN; i += 256) sm[brev9(i)] = make_float2(row[i], 0.0f);
    __syncthreads();
    fft512_stages(sm, tid, -1.0f);
    cplx* orow = out + (size_t)rid * WN;
    for (int i = tid; i < WN; i += 256) orow[i] = sm[i];
}

// Row-wise inverse FFT (complex in -> complex out, no scaling). grid (BN*HN), block 256.
__global__ void row_fft_inv(const cplx* __restrict__ in, cplx* __restrict__ out){
    const int rid = blockIdx.x;
    __shared__ cplx sm[WN];
    const int tid = threadIdx.x;
    const cplx* row = in + (size_t)rid * WN;
    for (int i = tid; i < WN; i += 256) sm[brev9(i)] = row[i];
    __syncthreads();
    fft512_stages(sm, tid, 1.0f);
    cplx* orow = out + (size_t)rid * WN;
    for (int i = tid; i < WN; i += 256) orow[i] = sm[i];
}

// Column-wise FFT, 8 columns per block, in place. grid (WN/8, BN), block 256.
__global__ void col_fft(cplx* __restrict__ buf, float sign){
    const int b  = blockIdx.y;
    const int w0 = blockIdx.x * 8;
    const int tid = threadIdx.x;
    __shared__ cplx sm[HN][9];     // pad 8 -> 9 to spread banks
    __shared__ cplx tw[256];
    cplx* base = buf + (size_t)b * HN * WN + w0;
    for (int idx = tid; idx < HN * 8; idx += 256){
        int h = idx >> 3, c = idx & 7;
        sm[brev9(h)][c] = base[(size_t)h * WN + c];
    }
    __syncthreads();
    for (int st = 1; st <= 9; ++st){
        const int m = 1 << st, half = m >> 1;
        {
            const int j = tid & (half - 1);
            float sv, cv; sincosf(sign * TWO_PI * (float)j / (float)m, &sv, &cv);
            tw[tid] = make_float2(cv, sv);
        }
        __syncthreads();
        for (int t2 = tid; t2 < 256 * 8; t2 += 256){
            int c = t2 & 7, k = t2 >> 3;
            int j = k & (half - 1), grp = k >> (st - 1);
            int i0 = grp * m + j, i1 = i0 + half;
            cplx a  = sm[i0][c];
            cplx tt = cmul(tw[k], sm[i1][c]);
            sm[i0][c] = make_float2(a.x + tt.x, a.y + tt.y);
            sm[i1][c] = make_float2(a.x - tt.x, a.y - tt.y);
        }
        __syncthreads();
    }
    for (int idx = tid; idx < HN * 8; idx += 256){
        int h = idx >> 3, c = idx & 7;
        base[(size_t)h * WN + c] = sm[h][c];
    }
}

// P = F_src * conj(F_tgt), stored over F_tgt (buf1).
__global__ void cross_power(cplx* __restrict__ ft, const cplx* __restrict__ fs){
    size_t i = (size_t)blockIdx.x * 256 + threadIdx.x;
    cplx t = ft[i], s = fs[i];
    ft[i] = make_float2(s.x * t.x + s.y * t.y, s.y * t.x - s.x * t.y);
}

// Per-batch argmax of |cc|^2 -> coarse shifts + upsample offsets. grid (BN), block 256.
__global__ void coarse_argmax(const cplx* __restrict__ cc, float* __restrict__ small){
    const int b = blockIdx.x;
    const int tid = threadIdx.x;
    const cplx* p = cc + (size_t)b * HN * WN;
    float best = -1.0f; int bidx = 0x7fffffff;
    for (int i = tid; i < HN * WN; i += 256){
        cplx v = p[i];
        float m = v.x * v.x + v.y * v.y;
        if (m > best){ best = m; bidx = i; }
    }
    __shared__ float vals[256];
    __shared__ int   idxs[256];
    vals[tid] = best; idxs[tid] = bidx;
    __syncthreads();
    for (int s = 128; s > 0; s >>= 1){
        if (tid < s){
            if (vals[tid + s] > vals[tid] ||
                (vals[tid + s] == vals[tid] && idxs[tid + s] < idxs[tid])){
                vals[tid] = vals[tid + s]; idxs[tid] = idxs[tid + s];
            }
        }
        __syncthreads();
    }
    if (tid == 0){
        int idx = idxs[0];
        int row = idx / WN, col = idx % WN;
        float sr = (row > HN / 2) ? (float)(row - HN) : (float)row;  // strictly > midpoint
        float sc = (col > WN / 2) ? (float)(col - WN) : (float)col;
        small[b * 4 + 0] = sr;
        small[b * 4 + 1] = sc;
        small[b * 4 + 2] = DFTSHIFT - sr * UFV;  // off0
        small[b * 4 + 3] = DFTSHIFT - sc * UFV;  // off1
    }
}

// T[b][r][w] = sum_h row_k[r][h] * conj(P[b][h][w]).  grid (WN/64, BN), block 256.
// Threads: w = 64-lane slice, rbase = tid>>6 covers r = rbase*8+u.
__global__ void upsample_T(const cplx* __restrict__ P, const float* __restrict__ small,
                           cplx* __restrict__ Tb){
    const int b = blockIdx.y;
    const int tid = threadIdx.x;
    const int w = blockIdx.x * 64 + (tid & 63);
    const int rbase = tid >> 6;  // 0..3
    const float off0 = small[b * 4 + 2];
    const float CC = TWO_PI / (HN * UFV);
    __shared__ float2 rk[REGION][128];
    cplx acc[8];
    #pragma unroll
    for (int u = 0; u < 8; ++u) acc[u] = make_float2(0.f, 0.f);
    for (int h0 = 0; h0 < HN; h0 += 128){
        __syncthreads();
        for (int idx = tid; idx < REGION * 128; idx += 256){
            int r = idx >> 7, hh = idx & 127;
            int h = h0 + hh;
            float fr = (h < HN / 2) ? (float)h : (float)(h - HN);
            float sv, cv; sincosf(-CC * ((float)r - off0) * fr, &sv, &cv);
            rk[r][hh] = make_float2(cv, sv);
        }
        __syncthreads();
        const cplx* pcol = P + ((size_t)b * HN + h0) * WN + w;
        for (int hh = 0; hh < 128; ++hh){
            cplx p = pcol[(size_t)hh * WN];
            p.y = -p.y;  // conj(P)
            #pragma unroll
            for (int u = 0; u < 8; ++u){
                int r = rbase * 8 + u;
                if (r < REGION) acc[u] = cadd(acc[u], cmul(rk[r][hh], p));
            }
        }
    }
    #pragma unroll
    for (int u = 0; u < 8; ++u){
        int r = rbase * 8 + u;
        if (r < REGION) Tb[((size_t)b * REGION + r) * WN + w] = acc[u];
    }
}

// U = T @ col_k, argmax |U|^2, final shifts. grid (BN), block 256.
__global__ void upsample_final(const cplx* __restrict__ Tb, const float* __restrict__ small,
                               float* __restrict__ out){
    const int b = blockIdx.x;
    const int tid = threadIdx.x;
    const float off1 = small[b * 4 + 3];
    const float CC = TWO_PI / (WN * UFV);
    __shared__ float2 ck[128][REGION];   // [ww][c]
    __shared__ float2 Ts[REGION][128];
    cplx acc[4];
    #pragma unroll
    for (int q = 0; q < 4; ++q) acc[q] = make_float2(0.f, 0.f);
    for (int w0 = 0; w0 < WN; w0 += 128){
        __syncthreads();
        for (int idx = tid; idx < 128 * REGION; idx += 256){
            int ww = idx / REGION, c = idx - ww * REGION;
            int w = w0 + ww;
            float fw = (w < WN / 2) ? (float)w : (float)(w - WN);
            float sv, cv; sincosf(-CC * fw * ((float)c - off1), &sv, &cv);
            ck[ww][c] = make_float2(cv, sv);
        }
        for (int idx = tid; idx < REGION * 128; idx += 256){
            int r = idx >> 7, ww = idx & 127;
            Ts[r][ww] = Tb[((size_t)b * REGION + r) * WN + w0 + ww];
        }
        __syncthreads();
        #pragma unroll
        for (int q = 0; q < 4; ++q){
            int o = tid + 256 * q;
            if (o < REGION * REGION){
                int r = o / REGION, c = o - r * REGION;
                for (int ww = 0; ww < 128; ++ww)
                    acc[q] = cadd(acc[q], cmul(Ts[r][ww], ck[ww][c]));
            }
        }
    }
    float best = -1.0f; int bidx = 0x7fffffff;
    #pragma unroll
    for (int q = 0; q < 4; ++q){
        int o = tid + 256 * q;
        if (o < REGION * REGION){
            float m = acc[q].x * acc[q].x + acc[q].y * acc[q].y;
            if (m > best){ best = m; bidx = o; }
        }
    }
    __shared__ float vals[256];
    __shared__ int   idxs[256];
    vals[tid] = best; idxs[tid] = bidx;
    __syncthreads();
    for (int s = 128; s > 0; s >>= 1){
        if (tid < s){
            if (vals[tid + s] > vals[tid] ||
                (vals[tid + s] == vals[tid] && idxs[tid + s] < idxs[tid])){
                vals[tid] = vals[tid + s]; idxs[tid] = idxs[tid + s];
            }
        }
        __syncthreads();
    }
    if (tid == 0){
        int o = idxs[0];
        float r = (float)(o / REGION) - DFTSHIFT;
        float c = (float)(o % REGION) - DFTSHIFT;
        out[b * 2 + 0] = small[b * 4 + 0] + r / UFV;
        out[b * 2 + 1] = small[b * 4 + 1] + c / UFV;
    }
}

extern "C" void kernel_launch(void* const* d_in, const int* in_sizes, int n_in,
                              void* d_out, int out_size, void* d_ws, size_t ws_size,
                              hipStream_t stream){
    const float* tgt = (const float*)d_in[0];
    const float* src = (const float*)d_in[1];
    float* out = (float*)d_out;

    const size_t BIG = (size_t)BN * HN * WN;      // 8,388,608 complex = 67 MB
    cplx* buf1 = (cplx*)d_ws;                     // F_tgt, then P (image_product)
    cplx* buf2 = buf1 + BIG;                      // F_src, then cross_corr, then T
    float* small = (float*)(buf2 + BIG);          // 32 * 4 floats

    dim3 blk(256);
    // forward fft2 of both images
    row_fft_fwd<<<dim3(BN * HN, 2), blk, 0, stream>>>(tgt, src, buf1, buf2);
    col_fft<<<dim3(WN / 8, BN), blk, 0, stream>>>(buf1, -1.0f);
    col_fft<<<dim3(WN / 8, BN), blk, 0, stream>>>(buf2, -1.0f);
    // cross-power spectrum into buf1
    cross_power<<<dim3((unsigned)(BIG / 256)), blk, 0, stream>>>(buf1, buf2);
    // ifft2 (unscaled) into buf2
    row_fft_inv<<<dim3(BN * HN), blk, 0, stream>>>(buf1, buf2);
    col_fft<<<dim3(WN / 8, BN), blk, 0, stream>>>(buf2, 1.0f);
    // coarse peak
    coarse_argmax<<<dim3(BN), blk, 0, stream>>>(buf2, small);
    // upsampled DFT refinement (buf2 reused for T after coarse_argmax consumed it)
    cplx* Tb = buf2;
    upsample_T<<<dim3(WN / 64, BN), blk, 0, stream>>>(buf1, small, Tb);
    upsample_final<<<dim3(BN), blk, 0, stream>>>(Tb, small, out);
}

// Round 2
// 646.823 us; speedup vs baseline: 1.4961x; 1.4961x over previous
//
#include <hip/hip_runtime.h>
#include <math.h>

#define BN 32
#define HN 512
#define WN 512
#define REGION 30
#define UFV 20.0f
#define DFTSHIFT 15.0f
#define TWO_PI 6.2831853071795864769f

typedef float2 cplx;

__device__ __forceinline__ cplx cmul(cplx a, cplx b){
    return make_float2(a.x*b.x - a.y*b.y, a.x*b.y + a.y*b.x);
}
__device__ __forceinline__ cplx cadd(cplx a, cplx b){
    return make_float2(a.x + b.x, a.y + b.y);
}
__device__ __forceinline__ int brev9(int i){ return (int)(__brev((unsigned)i) >> 23); }

// in-LDS 512-pt radix-2 DIT FFT, 256 threads, data pre-bit-reversed, twiddles from table
__device__ __forceinline__ void fft512_tbl(cplx* sm, const float2* tw, int tid){
    #pragma unroll
    for (int st = 1; st <= 9; ++st){
        const int m = 1 << st, half = m >> 1;
        const int j  = tid & (half - 1);
        const int i0 = ((tid >> (st - 1)) << st) + j, i1 = i0 + half;
        cplx w = tw[j << (9 - st)];
        cplx a = sm[i0];
        cplx t = cmul(w, sm[i1]);
        sm[i0] = make_float2(a.x + t.x, a.y + t.y);
        sm[i1] = make_float2(a.x - t.x, a.y - t.y);
        __syncthreads();
    }
}

// Row-wise forward FFT of both real inputs. grid (BN*HN, 2), block 256.
__global__ void row_fft_fwd(const float* __restrict__ tin, const float* __restrict__ sin_,
                            cplx* __restrict__ ft, cplx* __restrict__ fs){
    const int rid = blockIdx.x;
    const float* in = (blockIdx.y == 0) ? tin : sin_;
    cplx* out       = (blockIdx.y == 0) ? ft  : fs;
    __shared__ cplx sm[WN];
    __shared__ float2 tw[256];
    const int tid = threadIdx.x;
    { float sv, cv; sincosf(-TWO_PI * (float)tid * (1.0f/512.0f), &sv, &cv);
      tw[tid] = make_float2(cv, sv); }
    const float* row = in + (size_t)rid * WN;
    #pragma unroll
    for (int u = 0; u < 2; ++u){
        int i = tid + u * 256;
        sm[brev9(i)] = make_float2(row[i], 0.0f);
    }
    __syncthreads();
    fft512_tbl(sm, tw, tid);
    cplx* orow = out + (size_t)rid * WN;
    #pragma unroll
    for (int u = 0; u < 2; ++u){ int i = tid + u * 256; orow[i] = sm[i]; }
}

// Column-wise forward FFT of BOTH freq buffers, 8 cols/block. grid (WN/8, BN, 2).
__global__ void col_fft_fwd2(cplx* __restrict__ b1, cplx* __restrict__ b2){
    cplx* buf = (blockIdx.z == 0) ? b1 : b2;
    const int b  = blockIdx.y;
    const int w0 = blockIdx.x * 8;
    const int tid = threadIdx.x;
    __shared__ cplx sm[HN][9];
    __shared__ float2 tw[256];
    { float sv, cv; sincosf(-TWO_PI * (float)tid * (1.0f/512.0f), &sv, &cv);
      tw[tid] = make_float2(cv, sv); }
    cplx* base = buf + (size_t)b * HN * WN + w0;
    for (int idx = tid; idx < HN * 8; idx += 256){
        int h = idx >> 3, c = idx & 7;
        sm[brev9(h)][c] = base[(size_t)h * WN + c];
    }
    __syncthreads();
    for (int st = 1; st <= 9; ++st){
        const int m = 1 << st, half = m >> 1;
        for (int t2 = tid; t2 < 256 * 8; t2 += 256){
            int c = t2 & 7, k = t2 >> 3;
            int j = k & (half - 1);
            int i0 = ((k >> (st - 1)) << st) + j, i1 = i0 + half;
            cplx w  = tw[j << (9 - st)];
            cplx a  = sm[i0][c];
            cplx tt = cmul(w, sm[i1][c]);
            sm[i0][c] = make_float2(a.x + tt.x, a.y + tt.y);
            sm[i1][c] = make_float2(a.x - tt.x, a.y - tt.y);
        }
        __syncthreads();
    }
    for (int idx = tid; idx < HN * 8; idx += 256){
        int h = idx >> 3, c = idx & 7;
        base[(size_t)h * WN + c] = sm[h][c];
    }
}

// P = F_src * conj(F_tgt) written to buf1 (over F_tgt), then row-wise inverse FFT
// of P written to buf2 (over F_src). grid (BN*HN), block 256.
__global__ void cross_rowinv(cplx* __restrict__ P, cplx* __restrict__ B2){
    const int rid = blockIdx.x;
    __shared__ cplx sm[WN];
    __shared__ float2 tw[256];
    const int tid = threadIdx.x;
    { float sv, cv; sincosf(TWO_PI * (float)tid * (1.0f/512.0f), &sv, &cv);
      tw[tid] = make_float2(cv, sv); }
    cplx* prow = P + (size_t)rid * WN;
    cplx* brow = B2 + (size_t)rid * WN;
    #pragma unroll
    for (int u = 0; u < 2; ++u){
        int i = tid + u * 256;
        cplx t = prow[i], s = brow[i];
        cplx p = make_float2(s.x * t.x + s.y * t.y, s.y * t.x - s.x * t.y);
        prow[i] = p;
        sm[brev9(i)] = p;
    }
    __syncthreads();
    fft512_tbl(sm, tw, tid);
    #pragma unroll
    for (int u = 0; u < 2; ++u){ int i = tid + u * 256; brow[i] = sm[i]; }
}

// Column-wise inverse FFT + per-block argmax of |cc|^2 (no global writeback).
// grid (WN/8, BN), block 256. cand[b*64+bx] = (maxval, bitcast idx).
__global__ void colinv_argmax(const cplx* __restrict__ buf, float2* __restrict__ cand){
    const int b  = blockIdx.y;
    const int w0 = blockIdx.x * 8;
    const int tid = threadIdx.x;
    __shared__ cplx sm[HN][9];
    __shared__ float2 tw[256];
    { float sv, cv; sincosf(TWO_PI * (float)tid * (1.0f/512.0f), &sv, &cv);
      tw[tid] = make_float2(cv, sv); }
    const cplx* base = buf + (size_t)b * HN * WN + w0;
    for (int idx = tid; idx < HN * 8; idx += 256){
        int h = idx >> 3, c = idx & 7;
        sm[brev9(h)][c] = base[(size_t)h * WN + c];
    }
    __syncthreads();
    for (int st = 1; st <= 9; ++st){
        const int m = 1 << st, half = m >> 1;
        for (int t2 = tid; t2 < 256 * 8; t2 += 256){
            int c = t2 & 7, k = t2 >> 3;
            int j = k & (half - 1);
            int i0 = ((k >> (st - 1)) << st) + j, i1 = i0 + half;
            cplx w  = tw[j << (9 - st)];
            cplx a  = sm[i0][c];
            cplx tt = cmul(w, sm[i1][c]);
            sm[i0][c] = make_float2(a.x + tt.x, a.y + tt.y);
            sm[i1][c] = make_float2(a.x - tt.x, a.y - tt.y);
        }
        __syncthreads();
    }
    // local argmax; iteration order (h asc, c asc) is monotone in global index
    float best = -1.0f; int bidx = 0x7fffffff;
    for (int idx = tid; idx < HN * 8; idx += 256){
        int h = idx >> 3, c = idx & 7;
        cplx v = sm[h][c];
        float mm = v.x * v.x + v.y * v.y;
        if (mm > best){ best = mm; bidx = h * WN + w0 + c; }
    }
    __shared__ float vals[256];
    __shared__ int   idxs[256];
    vals[tid] = best; idxs[tid] = bidx;
    __syncthreads();
    for (int s = 128; s > 0; s >>= 1){
        if (tid < s){
            if (vals[tid + s] > vals[tid] ||
                (vals[tid + s] == vals[tid] && idxs[tid + s] < idxs[tid])){
                vals[tid] = vals[tid + s]; idxs[tid] = idxs[tid + s];
            }
        }
        __syncthreads();
    }
    if (tid == 0) cand[b * 64 + blockIdx.x] = make_float2(vals[0], __int_as_float(idxs[0]));
}

// Reduce 64 candidates per batch -> coarse shifts + upsample offsets. grid BN, block 64.
__global__ void coarse_reduce(const float2* __restrict__ cand, float* __restrict__ small){
    const int b = blockIdx.x, t = threadIdx.x;
    float2 c = cand[b * 64 + t];
    float v = c.x; int ix = __float_as_int(c.y);
    for (int off = 32; off > 0; off >>= 1){
        float v2 = __shfl_down(v, off);
        int   i2 = __shfl_down(ix, off);
        if (v2 > v || (v2 == v && i2 < ix)){ v = v2; ix = i2; }
    }
    if (t == 0){
        int row = ix / WN, col = ix % WN;
        float sr = (row > HN / 2) ? (float)(row - HN) : (float)row;
        float sc = (col > WN / 2) ? (float)(col - WN) : (float)col;
        small[b * 4 + 0] = sr;
        small[b * 4 + 1] = sc;
        small[b * 4 + 2] = DFTSHIFT - sr * UFV;
        small[b * 4 + 3] = DFTSHIFT - sc * UFV;
    }
}

// T[b][r][w] = sum_h row_k[r][h] * conj(P[b][h][w]).  grid (WN/64, BN), block 256.
__global__ void upsample_T(const cplx* __restrict__ P, const float* __restrict__ small,
                           cplx* __restrict__ Tb){
    const int b = blockIdx.y;
    const int tid = threadIdx.x;
    const int w = blockIdx.x * 64 + (tid & 63);
    const int rbase = tid >> 6;  // 0..3
    const float off0 = small[b * 4 + 2];
    const float CC = TWO_PI / (HN * UFV);
    __shared__ float2 rk[REGION][128];
    cplx acc[8];
    #pragma unroll
    for (int u = 0; u < 8; ++u) acc[u] = make_float2(0.f, 0.f);
    for (int h0 = 0; h0 < HN; h0 += 128){
        __syncthreads();
        for (int idx = tid; idx < REGION * 128; idx += 256){
            int r = idx >> 7, hh = idx & 127;
            int h = h0 + hh;
            float fr = (h < HN / 2) ? (float)h : (float)(h - HN);
            float sv, cv; sincosf(-CC * ((float)r - off0) * fr, &sv, &cv);
            rk[r][hh] = make_float2(cv, sv);
        }
        __syncthreads();
        const cplx* pcol = P + ((size_t)b * HN + h0) * WN + w;
        for (int hh = 0; hh < 128; ++hh){
            cplx p = pcol[(size_t)hh * WN];
            p.y = -p.y;  // conj(P)
            #pragma unroll
            for (int u = 0; u < 8; ++u){
                int r = rbase * 8 + u;
                if (r < REGION) acc[u] = cadd(acc[u], cmul(rk[r][hh], p));
            }
        }
    }
    #pragma unroll
    for (int u = 0; u < 8; ++u){
        int r = rbase * 8 + u;
        if (r < REGION) Tb[((size_t)b * REGION + r) * WN + w] = acc[u];
    }
}

// U = T @ col_k, argmax |U|^2, final shifts. grid (BN), block 256.
__global__ void upsample_final(const cplx* __restrict__ Tb, const float* __restrict__ small,
                               float* __restrict__ out){
    const int b = blockIdx.x;
    const int tid = threadIdx.x;
    const float off1 = small[b * 4 + 3];
    const float CC = TWO_PI / (WN * UFV);
    __shared__ float2 ck[128][REGION];   // [ww][c]
    __shared__ float2 Ts[REGION][128];
    cplx acc[4];
    #pragma unroll
    for (int q = 0; q < 4; ++q) acc[q] = make_float2(0.f, 0.f);
    for (int w0 = 0; w0 < WN; w0 += 128){
        __syncthreads();
        for (int idx = tid; idx < 128 * REGION; idx += 256){
            int ww = idx / REGION, c = idx - ww * REGION;
            int w = w0 + ww;
            float fw = (w < WN / 2) ? (float)w : (float)(w - WN);
            float sv, cv; sincosf(-CC * fw * ((float)c - off1), &sv, &cv);
            ck[ww][c] = make_float2(cv, sv);
        }
        for (int idx = tid; idx < REGION * 128; idx += 256){
            int r = idx >> 7, ww = idx & 127;
            Ts[r][ww] = Tb[((size_t)b * REGION + r) * WN + w0 + ww];
        }
        __syncthreads();
        #pragma unroll
        for (int q = 0; q < 4; ++q){
            int o = tid + 256 * q;
            if (o < REGION * REGION){
                int r = o / REGION, c = o - r * REGION;
                for (int ww = 0; ww < 128; ++ww)
                    acc[q] = cadd(acc[q], cmul(Ts[r][ww], ck[ww][c]));
            }
        }
    }
    float best = -1.0f; int bidx = 0x7fffffff;
    #pragma unroll
    for (int q = 0; q < 4; ++q){
        int o = tid + 256 * q;
        if (o < REGION * REGION){
            float m = acc[q].x * acc[q].x + acc[q].y * acc[q].y;
            if (m > best){ best = m; bidx = o; }
        }
    }
    __shared__ float vals[256];
    __shared__ int   idxs[256];
    vals[tid] = best; idxs[tid] = bidx;
    __syncthreads();
    for (int s = 128; s > 0; s >>= 1){
        if (tid < s){
            if (vals[tid + s] > vals[tid] ||
                (vals[tid + s] == vals[tid] && idxs[tid + s] < idxs[tid])){
                vals[tid] = vals[tid + s]; idxs[tid] = idxs[tid + s];
            }
        }
        __syncthreads();
    }
    if (tid == 0){
        int o = idxs[0];
        float r = (float)(o / REGION) - DFTSHIFT;
        float c = (float)(o % REGION) - DFTSHIFT;
        out[b * 2 + 0] = small[b * 4 + 0] + r / UFV;
        out[b * 2 + 1] = small[b * 4 + 1] + c / UFV;
    }
}

extern "C" void kernel_launch(void* const* d_in, const int* in_sizes, int n_in,
                              void* d_out, int out_size, void* d_ws, size_t ws_size,
                              hipStream_t stream){
    const float* tgt = (const float*)d_in[0];
    const float* src = (const float*)d_in[1];
    float* out = (float*)d_out;

    const size_t BIG = (size_t)BN * HN * WN;      // 8,388,608 complex = 67 MB
    cplx* buf1 = (cplx*)d_ws;                     // F_tgt -> P (image_product)
    cplx* buf2 = buf1 + BIG;                      // F_src -> ifft rows -> T
    float* small = (float*)(buf2 + BIG);          // 32 * 4 floats
    float2* cand = (float2*)(small + 128);        // 32 * 64 candidates (16 KB)

    dim3 blk(256);
    row_fft_fwd<<<dim3(BN * HN, 2), blk, 0, stream>>>(tgt, src, buf1, buf2);
    col_fft_fwd2<<<dim3(WN / 8, BN, 2), blk, 0, stream>>>(buf1, buf2);
    cross_rowinv<<<dim3(BN * HN), blk, 0, stream>>>(buf1, buf2);
    colinv_argmax<<<dim3(WN / 8, BN), blk, 0, stream>>>(buf2, cand);
    coarse_reduce<<<dim3(BN), dim3(64), 0, stream>>>(cand, small);
    cplx* Tb = buf2;
    upsample_T<<<dim3(WN / 64, BN), blk, 0, stream>>>(buf1, small, Tb);
    upsample_final<<<dim3(BN), blk, 0, stream>>>(Tb, small, out);
}

// Round 3
// 447.206 us; speedup vs baseline: 2.1638x; 1.4464x over previous
//
#include <hip/hip_runtime.h>
#include <math.h>

#define BN 32
#define HN 512
#define WN 512
#define REGION 30
#define UFV 20.0f
#define DFTSHIFT 15.0f
#define TWO_PI 6.2831853071795864769f
#define HS 8              // h-chunks for upsample_T partials
#define HCH (HN / HS)     // 64

typedef float2 cplx;

__device__ __forceinline__ cplx cmul(cplx a, cplx b){
    return make_float2(a.x*b.x - a.y*b.y, a.x*b.y + a.y*b.x);
}
__device__ __forceinline__ cplx cadd(cplx a, cplx b){
    return make_float2(a.x + b.x, a.y + b.y);
}
__device__ __forceinline__ int brev9(int i){ return (int)(__brev((unsigned)i) >> 23); }

// in-LDS 512-pt radix-2 DIT FFT, 256 threads, data pre-bit-reversed, twiddles from table
__device__ __forceinline__ void fft512_tbl(cplx* sm, const float2* tw, int tid){
    #pragma unroll
    for (int st = 1; st <= 9; ++st){
        const int m = 1 << st, half = m >> 1;
        const int j  = tid & (half - 1);
        const int i0 = ((tid >> (st - 1)) << st) + j, i1 = i0 + half;
        cplx w = tw[j << (9 - st)];
        cplx a = sm[i0];
        cplx t = cmul(w, sm[i1]);
        sm[i0] = make_float2(a.x + t.x, a.y + t.y);
        sm[i1] = make_float2(a.x - t.x, a.y - t.y);
        __syncthreads();
    }
}

// Row-wise forward FFT of both real inputs. grid (BN*HN, 2), block 256.
__global__ void row_fft_fwd(const float* __restrict__ tin, const float* __restrict__ sin_,
                            cplx* __restrict__ ft, cplx* __restrict__ fs){
    const int rid = blockIdx.x;
    const float* in = (blockIdx.y == 0) ? tin : sin_;
    cplx* out       = (blockIdx.y == 0) ? ft  : fs;
    __shared__ cplx sm[WN];
    __shared__ float2 tw[256];
    const int tid = threadIdx.x;
    { float sv, cv; sincosf(-TWO_PI * (float)tid * (1.0f/512.0f), &sv, &cv);
      tw[tid] = make_float2(cv, sv); }
    const float* row = in + (size_t)rid * WN;
    #pragma unroll
    for (int u = 0; u < 2; ++u){
        int i = tid + u * 256;
        sm[brev9(i)] = make_float2(row[i], 0.0f);
    }
    __syncthreads();
    fft512_tbl(sm, tw, tid);
    cplx* orow = out + (size_t)rid * WN;
    #pragma unroll
    for (int u = 0; u < 2; ++u){ int i = tid + u * 256; orow[i] = sm[i]; }
}

// Column-wise forward FFT of BOTH freq buffers, 8 cols/block. grid (WN/8, BN, 2).
__global__ void col_fft_fwd2(cplx* __restrict__ b1, cplx* __restrict__ b2){
    cplx* buf = (blockIdx.z == 0) ? b1 : b2;
    const int b  = blockIdx.y;
    const int w0 = blockIdx.x * 8;
    const int tid = threadIdx.x;
    __shared__ cplx sm[HN][9];
    __shared__ float2 tw[256];
    { float sv, cv; sincosf(-TWO_PI * (float)tid * (1.0f/512.0f), &sv, &cv);
      tw[tid] = make_float2(cv, sv); }
    cplx* base = buf + (size_t)b * HN * WN + w0;
    for (int idx = tid; idx < HN * 8; idx += 256){
        int h = idx >> 3, c = idx & 7;
        sm[brev9(h)][c] = base[(size_t)h * WN + c];
    }
    __syncthreads();
    for (int st = 1; st <= 9; ++st){
        const int m = 1 << st, half = m >> 1;
        for (int t2 = tid; t2 < 256 * 8; t2 += 256){
            int c = t2 & 7, k = t2 >> 3;
            int j = k & (half - 1);
            int i0 = ((k >> (st - 1)) << st) + j, i1 = i0 + half;
            cplx w  = tw[j << (9 - st)];
            cplx a  = sm[i0][c];
            cplx tt = cmul(w, sm[i1][c]);
            sm[i0][c] = make_float2(a.x + tt.x, a.y + tt.y);
            sm[i1][c] = make_float2(a.x - tt.x, a.y - tt.y);
        }
        __syncthreads();
    }
    for (int idx = tid; idx < HN * 8; idx += 256){
        int h = idx >> 3, c = idx & 7;
        base[(size_t)h * WN + c] = sm[h][c];
    }
}

// P = F_src * conj(F_tgt) written to buf1 (over F_tgt), then row-wise inverse FFT
// of P written to buf2 (over F_src). grid (BN*HN), block 256.
__global__ void cross_rowinv(cplx* __restrict__ P, cplx* __restrict__ B2){
    const int rid = blockIdx.x;
    __shared__ cplx sm[WN];
    __shared__ float2 tw[256];
    const int tid = threadIdx.x;
    { float sv, cv; sincosf(TWO_PI * (float)tid * (1.0f/512.0f), &sv, &cv);
      tw[tid] = make_float2(cv, sv); }
    cplx* prow = P + (size_t)rid * WN;
    cplx* brow = B2 + (size_t)rid * WN;
    #pragma unroll
    for (int u = 0; u < 2; ++u){
        int i = tid + u * 256;
        cplx t = prow[i], s = brow[i];
        cplx p = make_float2(s.x * t.x + s.y * t.y, s.y * t.x - s.x * t.y);
        prow[i] = p;
        sm[brev9(i)] = p;
    }
    __syncthreads();
    fft512_tbl(sm, tw, tid);
    #pragma unroll
    for (int u = 0; u < 2; ++u){ int i = tid + u * 256; brow[i] = sm[i]; }
}

// Column-wise inverse FFT + per-block argmax of |cc|^2 (no global writeback).
// grid (WN/8, BN), block 256. cand[b*64+bx] = (maxval, bitcast idx).
__global__ void colinv_argmax(const cplx* __restrict__ buf, float2* __restrict__ cand){
    const int b  = blockIdx.y;
    const int w0 = blockIdx.x * 8;
    const int tid = threadIdx.x;
    __shared__ cplx sm[HN][9];
    __shared__ float2 tw[256];
    { float sv, cv; sincosf(TWO_PI * (float)tid * (1.0f/512.0f), &sv, &cv);
      tw[tid] = make_float2(cv, sv); }
    const cplx* base = buf + (size_t)b * HN * WN + w0;
    for (int idx = tid; idx < HN * 8; idx += 256){
        int h = idx >> 3, c = idx & 7;
        sm[brev9(h)][c] = base[(size_t)h * WN + c];
    }
    __syncthreads();
    for (int st = 1; st <= 9; ++st){
        const int m = 1 << st, half = m >> 1;
        for (int t2 = tid; t2 < 256 * 8; t2 += 256){
            int c = t2 & 7, k = t2 >> 3;
            int j = k & (half - 1);
            int i0 = ((k >> (st - 1)) << st) + j, i1 = i0 + half;
            cplx w  = tw[j << (9 - st)];
            cplx a  = sm[i0][c];
            cplx tt = cmul(w, sm[i1][c]);
            sm[i0][c] = make_float2(a.x + tt.x, a.y + tt.y);
            sm[i1][c] = make_float2(a.x - tt.x, a.y - tt.y);
        }
        __syncthreads();
    }
    float best = -1.0f; int bidx = 0x7fffffff;
    for (int idx = tid; idx < HN * 8; idx += 256){
        int h = idx >> 3, c = idx & 7;
        cplx v = sm[h][c];
        float mm = v.x * v.x + v.y * v.y;
        if (mm > best){ best = mm; bidx = h * WN + w0 + c; }
    }
    __shared__ float vals[256];
    __shared__ int   idxs[256];
    vals[tid] = best; idxs[tid] = bidx;
    __syncthreads();
    for (int s = 128; s > 0; s >>= 1){
        if (tid < s){
            if (vals[tid + s] > vals[tid] ||
                (vals[tid + s] == vals[tid] && idxs[tid + s] < idxs[tid])){
                vals[tid] = vals[tid + s]; idxs[tid] = idxs[tid + s];
            }
        }
        __syncthreads();
    }
    if (tid == 0) cand[b * 64 + blockIdx.x] = make_float2(vals[0], __int_as_float(idxs[0]));
}

// Reduce 64 candidates per batch -> coarse shifts + upsample offsets. grid BN, block 64.
__global__ void coarse_reduce(const float2* __restrict__ cand, float* __restrict__ small){
    const int b = blockIdx.x, t = threadIdx.x;
    float2 c = cand[b * 64 + t];
    float v = c.x; int ix = __float_as_int(c.y);
    for (int off = 32; off > 0; off >>= 1){
        float v2 = __shfl_down(v, off);
        int   i2 = __shfl_down(ix, off);
        if (v2 > v || (v2 == v && i2 < ix)){ v = v2; ix = i2; }
    }
    if (t == 0){
        int row = ix / WN, col = ix % WN;
        float sr = (row > HN / 2) ? (float)(row - HN) : (float)row;
        float sc = (col > WN / 2) ? (float)(col - WN) : (float)col;
        small[b * 4 + 0] = sr;
        small[b * 4 + 1] = sc;
        small[b * 4 + 2] = DFTSHIFT - sr * UFV;
        small[b * 4 + 3] = DFTSHIFT - sc * UFV;
    }
}

// Partial T: Tpart[hs][b][r][w] = sum_{h in chunk hs} rk[r][h] * conj(P[b][h][w]).
// grid (WN/128, BN, HS), block 256. Each thread: 2 adjacent w (float4), 8 r values.
__global__ void upsample_T(const cplx* __restrict__ P, const float* __restrict__ small,
                           cplx* __restrict__ Tpart){
    const int b = blockIdx.y, hs = blockIdx.z;
    const int tid = threadIdx.x;
    const int lane = tid & 63;            // w-pair
    const int rbase = tid >> 6;           // 0..3 (wave-uniform)
    const int w = blockIdx.x * 128 + lane * 2;
    const int h0 = hs * HCH;
    const float off0 = small[b * 4 + 2];
    const float CC = TWO_PI / (HN * UFV);
    __shared__ float2 rk[REGION][HCH];    // 15360 B
    for (int idx = tid; idx < REGION * HCH; idx += 256){
        int r = idx >> 6, hh = idx & (HCH - 1);
        int h = h0 + hh;
        float fr = (h < HN / 2) ? (float)h : (float)(h - HN);
        float sv, cv; sincosf(-CC * ((float)r - off0) * fr, &sv, &cv);
        rk[r][hh] = make_float2(cv, sv);
    }
    __syncthreads();
    cplx a0[8], a1[8];
    #pragma unroll
    for (int u = 0; u < 8; ++u){ a0[u] = make_float2(0.f,0.f); a1[u] = make_float2(0.f,0.f); }
    const cplx* pc = P + ((size_t)b * HN + h0) * WN + w;
    for (int hh = 0; hh < HCH; hh += 8){
        float4 pv[8];
        #pragma unroll
        for (int k = 0; k < 8; ++k)
            pv[k] = *(const float4*)(pc + (size_t)(hh + k) * WN);
        #pragma unroll
        for (int k = 0; k < 8; ++k){
            cplx p0 = make_float2(pv[k].x, -pv[k].y);   // conj(P)
            cplx p1 = make_float2(pv[k].z, -pv[k].w);
            #pragma unroll
            for (int u = 0; u < 8; ++u){
                int r = rbase * 8 + u;
                if (r < REGION){
                    cplx wv = rk[r][hh + k];
                    a0[u] = cadd(a0[u], cmul(wv, p0));
                    a1[u] = cadd(a1[u], cmul(wv, p1));
                }
            }
        }
    }
    #pragma unroll
    for (int u = 0; u < 8; ++u){
        int r = rbase * 8 + u;
        if (r < REGION){
            cplx* dst = Tpart + (((size_t)hs * BN + b) * REGION + r) * WN + w;
            dst[0] = a0[u]; dst[1] = a1[u];
        }
    }
}

// Deterministic sum of the HS partials. grid (BN*REGION*WN/256), block 256.
__global__ void reduce_T(const cplx* __restrict__ Tpart, cplx* __restrict__ T){
    const size_t STRIDE = (size_t)BN * REGION * WN;
    size_t i = (size_t)blockIdx.x * 256 + threadIdx.x;
    cplx s = make_float2(0.f, 0.f);
    #pragma unroll
    for (int hs = 0; hs < HS; ++hs) s = cadd(s, Tpart[(size_t)hs * STRIDE + i]);
    T[i] = s;
}

// U = T @ col_k, argmax |U|^2, final shifts. grid (BN), block 256.
__global__ void upsample_final(const cplx* __restrict__ Tb, const float* __restrict__ small,
                               float* __restrict__ out){
    const int b = blockIdx.x;
    const int tid = threadIdx.x;
    const float off1 = small[b * 4 + 3];
    const float CC = TWO_PI / (WN * UFV);
    __shared__ float2 ck[128][REGION];   // [ww][c]
    __shared__ float2 Ts[REGION][128];
    cplx acc[4];
    #pragma unroll
    for (int q = 0; q < 4; ++q) acc[q] = make_float2(0.f, 0.f);
    for (int w0 = 0; w0 < WN; w0 += 128){
        __syncthreads();
        for (int idx = tid; idx < 128 * REGION; idx += 256){
            int ww = idx / REGION, c = idx - ww * REGION;
            int w = w0 + ww;
            float fw = (w < WN / 2) ? (float)w : (float)(w - WN);
            float sv, cv; sincosf(-CC * fw * ((float)c - off1), &sv, &cv);
            ck[ww][c] = make_float2(cv, sv);
        }
        for (int idx = tid; idx < REGION * 128; idx += 256){
            int r = idx >> 7, ww = idx & 127;
            Ts[r][ww] = Tb[((size_t)b * REGION + r) * WN + w0 + ww];
        }
        __syncthreads();
        #pragma unroll
        for (int q = 0; q < 4; ++q){
            int o = tid + 256 * q;
            if (o < REGION * REGION){
                int r = o / REGION, c = o - r * REGION;
                for (int ww = 0; ww < 128; ++ww)
                    acc[q] = cadd(acc[q], cmul(Ts[r][ww], ck[ww][c]));
            }
        }
    }
    float best = -1.0f; int bidx = 0x7fffffff;
    #pragma unroll
    for (int q = 0; q < 4; ++q){
        int o = tid + 256 * q;
        if (o < REGION * REGION){
            float m = acc[q].x * acc[q].x + acc[q].y * acc[q].y;
            if (m > best){ best = m; bidx = o; }
        }
    }
    __shared__ float vals[256];
    __shared__ int   idxs[256];
    vals[tid] = best; idxs[tid] = bidx;
    __syncthreads();
    for (int s = 128; s > 0; s >>= 1){
        if (tid < s){
            if (vals[tid + s] > vals[tid] ||
                (vals[tid + s] == vals[tid] && idxs[tid + s] < idxs[tid])){
                vals[tid] = vals[tid + s]; idxs[tid] = idxs[tid + s];
            }
        }
        __syncthreads();
    }
    if (tid == 0){
        int o = idxs[0];
        float r = (float)(o / REGION) - DFTSHIFT;
        float c = (float)(o % REGION) - DFTSHIFT;
        out[b * 2 + 0] = small[b * 4 + 0] + r / UFV;
        out[b * 2 + 1] = small[b * 4 + 1] + c / UFV;
    }
}

extern "C" void kernel_launch(void* const* d_in, const int* in_sizes, int n_in,
                              void* d_out, int out_size, void* d_ws, size_t ws_size,
                              hipStream_t stream){
    const float* tgt = (const float*)d_in[0];
    const float* src = (const float*)d_in[1];
    float* out = (float*)d_out;

    const size_t BIG = (size_t)BN * HN * WN;      // 8,388,608 complex = 67 MB
    cplx* buf1 = (cplx*)d_ws;                     // F_tgt -> P (image_product)
    cplx* buf2 = buf1 + BIG;                      // F_src -> ifft rows -> Tpart/T
    float* small = (float*)(buf2 + BIG);          // 32 * 4 floats
    float2* cand = (float2*)(small + 128);        // 32 * 64 candidates

    const size_t TSTRIDE = (size_t)BN * REGION * WN;   // elements per T image set
    cplx* Tpart = buf2;                                // HS * TSTRIDE = 31.5 MB
    cplx* T     = buf2 + HS * TSTRIDE;                 // 3.9 MB (fits in buf2's 67 MB)

    dim3 blk(256);
    row_fft_fwd<<<dim3(BN * HN, 2), blk, 0, stream>>>(tgt, src, buf1, buf2);
    col_fft_fwd2<<<dim3(WN / 8, BN, 2), blk, 0, stream>>>(buf1, buf2);
    cross_rowinv<<<dim3(BN * HN), blk, 0, stream>>>(buf1, buf2);
    colinv_argmax<<<dim3(WN / 8, BN), blk, 0, stream>>>(buf2, cand);
    coarse_reduce<<<dim3(BN), dim3(64), 0, stream>>>(cand, small);
    upsample_T<<<dim3(WN / 128, BN, HS), blk, 0, stream>>>(buf1, small, Tpart);
    reduce_T<<<dim3((unsigned)(TSTRIDE / 256)), blk, 0, stream>>>(Tpart, T);
    upsample_final<<<dim3(BN), blk, 0, stream>>>(T, small, out);
}

// Round 4
// 334.619 us; speedup vs baseline: 2.8919x; 1.3365x over previous
//
#include <hip/hip_runtime.h>
#include <math.h>

#define BN 32
#define HN 512
#define WN 512
#define REGION 30
#define UFV 20.0f
#define DFTSHIFT 15.0f
#define TWO_PI 6.2831853071795864769f
#define HS 8              // h-chunks for upsample_T partials
#define HCH (HN / HS)     // 64

typedef float2 cplx;

__device__ __forceinline__ cplx cmul(cplx a, cplx b){
    return make_float2(a.x*b.x - a.y*b.y, a.x*b.y + a.y*b.x);
}
__device__ __forceinline__ cplx cadd(cplx a, cplx b){
    return make_float2(a.x + b.x, a.y + b.y);
}
__device__ __forceinline__ int brev9(int i){ return (int)(__brev((unsigned)i) >> 23); }
// 1D row-FFT LDS swizzle: spreads stride-2^st butterfly patterns to the 4-way float2 floor
__device__ __forceinline__ int swz(int i){ return i + (i >> 4); }        // needs 544 slots
// col-FFT LDS swizzle: 9 coprime to 16 spreads rows; XOR spreads the 8-col group
__device__ __forceinline__ int cswz(int h, int c){ return 9 * h + (c ^ (h & 7)); }

// in-LDS 512-pt radix-2 DIT FFT (swizzled layout), 256 threads, data pre-bit-reversed
__device__ __forceinline__ void fft512_swz(cplx* sm, const float2* tw, int tid){
    #pragma unroll
    for (int st = 1; st <= 9; ++st){
        const int m = 1 << st, half = m >> 1;
        const int j  = tid & (half - 1);
        const int i0 = ((tid >> (st - 1)) << st) + j, i1 = i0 + half;
        cplx w = tw[j << (9 - st)];
        const int a0 = swz(i0), a1 = swz(i1);
        cplx a = sm[a0];
        cplx t = cmul(w, sm[a1]);
        sm[a0] = make_float2(a.x + t.x, a.y + t.y);
        sm[a1] = make_float2(a.x - t.x, a.y - t.y);
        __syncthreads();
    }
}

// Packed row FFT: F_z rows of z = tgt + i*src. grid (BN*HN), block 256.
__global__ void row_fft_pack(const float* __restrict__ tgt, const float* __restrict__ src,
                             cplx* __restrict__ Fz){
    const int rid = blockIdx.x;
    __shared__ cplx sm[544];
    __shared__ float2 tw[256];
    const int tid = threadIdx.x;
    { float sv, cv; sincosf(-TWO_PI * (float)tid * (1.0f/512.0f), &sv, &cv);
      tw[tid] = make_float2(cv, sv); }
    const float* tr = tgt + (size_t)rid * WN;
    const float* sr = src + (size_t)rid * WN;
    #pragma unroll
    for (int u = 0; u < 2; ++u){
        int i = tid + u * 256;
        sm[swz(brev9(i))] = make_float2(tr[i], sr[i]);
    }
    __syncthreads();
    fft512_swz(sm, tw, tid);
    cplx* orow = Fz + (size_t)rid * WN;
    #pragma unroll
    for (int u = 0; u < 2; ++u){ int i = tid + u * 256; orow[i] = sm[swz(i)]; }
}

// Column-wise forward FFT of F_z, 8 cols/block, in place. grid (WN/8, BN).
__global__ void col_fft_fwd(cplx* __restrict__ buf){
    const int b  = blockIdx.y;
    const int w0 = blockIdx.x * 8;
    const int tid = threadIdx.x;
    __shared__ cplx sm[4608];
    __shared__ float2 tw[256];
    { float sv, cv; sincosf(-TWO_PI * (float)tid * (1.0f/512.0f), &sv, &cv);
      tw[tid] = make_float2(cv, sv); }
    cplx* base = buf + (size_t)b * HN * WN + w0;
    for (int idx = tid; idx < HN * 8; idx += 256){
        int h = idx >> 3, c = idx & 7;
        sm[cswz(brev9(h), c)] = base[(size_t)h * WN + c];
    }
    __syncthreads();
    for (int st = 1; st <= 9; ++st){
        const int m = 1 << st, half = m >> 1;
        for (int t2 = tid; t2 < 256 * 8; t2 += 256){
            int c = t2 & 7, k = t2 >> 3;
            int j = k & (half - 1);
            int i0 = ((k >> (st - 1)) << st) + j, i1 = i0 + half;
            cplx w  = tw[j << (9 - st)];
            const int a0 = cswz(i0, c), a1 = cswz(i1, c);
            cplx a  = sm[a0];
            cplx tt = cmul(w, sm[a1]);
            sm[a0] = make_float2(a.x + tt.x, a.y + tt.y);
            sm[a1] = make_float2(a.x - tt.x, a.y - tt.y);
        }
        __syncthreads();
    }
    for (int idx = tid; idx < HN * 8; idx += 256){
        int h = idx >> 3, c = idx & 7;
        base[(size_t)h * WN + c] = sm[cswz(h, c)];
    }
}

// Hermitian unpack + cross-power + row-wise inverse FFT, paired rows (h, N-h).
// grid (257, BN), block 256. P written in place over Fz; cc rows to cc.
__global__ void cross_rowinv_pair(cplx* __restrict__ Fz, cplx* __restrict__ cc){
    const int j = blockIdx.x, b = blockIdx.y;
    const int h1 = j, h2 = (HN - j) & (HN - 1);
    const int tid = threadIdx.x;
    __shared__ cplx sa[544], sb[544];
    __shared__ float2 tw[256];
    { float sv, cv; sincosf(TWO_PI * (float)tid * (1.0f/512.0f), &sv, &cv);
      tw[tid] = make_float2(cv, sv); }
    cplx* r1 = Fz + ((size_t)b * HN + h1) * WN;
    cplx* r2 = Fz + ((size_t)b * HN + h2) * WN;
    #pragma unroll
    for (int u = 0; u < 2; ++u){
        int i = tid + u * 256;
        sa[i] = r1[i]; sb[i] = r2[i];
    }
    __syncthreads();
    // P(k) = -i*(A-B)*conj(A+B)/4,  A = Fz(k), B = conj(Fz(-k))
    cplx P1[2], P2[2];
    #pragma unroll
    for (int u = 0; u < 2; ++u){
        int w  = tid + u * 256;
        int wN = (WN - w) & (WN - 1);
        { cplx A = sa[w];
          cplx B = sb[wN]; B.y = -B.y;
          cplx s = make_float2(A.x + B.x, A.y + B.y);
          cplx d = make_float2(A.x - B.x, A.y - B.y);
          cplx D = make_float2(d.x*s.x + d.y*s.y, d.y*s.x - d.x*s.y);  // d*conj(s)
          P1[u] = make_float2(0.25f * D.y, -0.25f * D.x); }
        { cplx A = sb[w];
          cplx B = sa[wN]; B.y = -B.y;
          cplx s = make_float2(A.x + B.x, A.y + B.y);
          cplx d = make_float2(A.x - B.x, A.y - B.y);
          cplx D = make_float2(d.x*s.x + d.y*s.y, d.y*s.x - d.x*s.y);
          P2[u] = make_float2(0.25f * D.y, -0.25f * D.x); }
    }
    __syncthreads();
    #pragma unroll
    for (int u = 0; u < 2; ++u){
        int w = tid + u * 256;
        r1[w] = P1[u];                     // in-place safe: block owns rows h1,h2
        r2[w] = P2[u];
        sa[swz(brev9(w))] = P1[u];
        sb[swz(brev9(w))] = P2[u];
    }
    __syncthreads();
    #pragma unroll
    for (int st = 1; st <= 9; ++st){       // dual inverse FFT
        const int m = 1 << st, half = m >> 1;
        const int jj = tid & (half - 1);
        const int i0 = ((tid >> (st - 1)) << st) + jj, i1 = i0 + half;
        cplx w = tw[jj << (9 - st)];
        const int a0 = swz(i0), a1 = swz(i1);
        cplx x0 = sa[a0], x1 = cmul(w, sa[a1]);
        sa[a0] = make_float2(x0.x + x1.x, x0.y + x1.y);
        sa[a1] = make_float2(x0.x - x1.x, x0.y - x1.y);
        cplx y0 = sb[a0], y1 = cmul(w, sb[a1]);
        sb[a0] = make_float2(y0.x + y1.x, y0.y + y1.y);
        sb[a1] = make_float2(y0.x - y1.x, y0.y - y1.y);
        __syncthreads();
    }
    cplx* c1 = cc + ((size_t)b * HN + h1) * WN;
    cplx* c2 = cc + ((size_t)b * HN + h2) * WN;
    #pragma unroll
    for (int u = 0; u < 2; ++u){
        int i = tid + u * 256;
        c1[i] = sa[swz(i)];
        c2[i] = sb[swz(i)];
    }
}

// Column-wise inverse FFT + per-block argmax of |cc|^2 (no global writeback).
// grid (WN/8, BN), block 256. cand[b*64+bx] = (maxval, bitcast idx).
__global__ void colinv_argmax(const cplx* __restrict__ buf, float2* __restrict__ cand){
    const int b  = blockIdx.y;
    const int w0 = blockIdx.x * 8;
    const int tid = threadIdx.x;
    __shared__ cplx sm[4608];
    __shared__ float2 tw[256];
    { float sv, cv; sincosf(TWO_PI * (float)tid * (1.0f/512.0f), &sv, &cv);
      tw[tid] = make_float2(cv, sv); }
    const cplx* base = buf + (size_t)b * HN * WN + w0;
    for (int idx = tid; idx < HN * 8; idx += 256){
        int h = idx >> 3, c = idx & 7;
        sm[cswz(brev9(h), c)] = base[(size_t)h * WN + c];
    }
    __syncthreads();
    for (int st = 1; st <= 9; ++st){
        const int m = 1 << st, half = m >> 1;
        for (int t2 = tid; t2 < 256 * 8; t2 += 256){
            int c = t2 & 7, k = t2 >> 3;
            int j = k & (half - 1);
            int i0 = ((k >> (st - 1)) << st) + j, i1 = i0 + half;
            cplx w  = tw[j << (9 - st)];
            const int a0 = cswz(i0, c), a1 = cswz(i1, c);
            cplx a  = sm[a0];
            cplx tt = cmul(w, sm[a1]);
            sm[a0] = make_float2(a.x + tt.x, a.y + tt.y);
            sm[a1] = make_float2(a.x - tt.x, a.y - tt.y);
        }
        __syncthreads();
    }
    float best = -1.0f; int bidx = 0x7fffffff;
    for (int idx = tid; idx < HN * 8; idx += 256){
        int h = idx >> 3, c = idx & 7;
        cplx v = sm[cswz(h, c)];
        float mm = v.x * v.x + v.y * v.y;
        if (mm > best){ best = mm; bidx = h * WN + w0 + c; }
    }
    __shared__ float vals[256];
    __shared__ int   idxs[256];
    vals[tid] = best; idxs[tid] = bidx;
    __syncthreads();
    for (int s = 128; s > 0; s >>= 1){
        if (tid < s){
            if (vals[tid + s] > vals[tid] ||
                (vals[tid + s] == vals[tid] && idxs[tid + s] < idxs[tid])){
                vals[tid] = vals[tid + s]; idxs[tid] = idxs[tid + s];
            }
        }
        __syncthreads();
    }
    if (tid == 0) cand[b * 64 + blockIdx.x] = make_float2(vals[0], __int_as_float(idxs[0]));
}

// Reduce 64 candidates per batch -> coarse shifts + upsample offsets. grid BN, block 64.
__global__ void coarse_reduce(const float2* __restrict__ cand, float* __restrict__ small){
    const int b = blockIdx.x, t = threadIdx.x;
    float2 c = cand[b * 64 + t];
    float v = c.x; int ix = __float_as_int(c.y);
    for (int off = 32; off > 0; off >>= 1){
        float v2 = __shfl_down(v, off);
        int   i2 = __shfl_down(ix, off);
        if (v2 > v || (v2 == v && i2 < ix)){ v = v2; ix = i2; }
    }
    if (t == 0){
        int row = ix / WN, col = ix % WN;
        float sr = (row > HN / 2) ? (float)(row - HN) : (float)row;
        float sc = (col > WN / 2) ? (float)(col - WN) : (float)col;
        small[b * 4 + 0] = sr;
        small[b * 4 + 1] = sc;
        small[b * 4 + 2] = DFTSHIFT - sr * UFV;
        small[b * 4 + 3] = DFTSHIFT - sc * UFV;
    }
}

// Partial T: Tpart[hs][b][r][w] = sum_{h in chunk hs} rk[r][h] * conj(P[b][h][w]).
// grid (WN/128, BN, HS), block 256. Each thread: 2 adjacent w (float4), 8 r values.
__global__ void upsample_T(const cplx* __restrict__ P, const float* __restrict__ small,
                           cplx* __restrict__ Tpart){
    const int b = blockIdx.y, hs = blockIdx.z;
    const int tid = threadIdx.x;
    const int lane = tid & 63;
    const int rbase = tid >> 6;
    const int w = blockIdx.x * 128 + lane * 2;
    const int h0 = hs * HCH;
    const float off0 = small[b * 4 + 2];
    const float CC = TWO_PI / (HN * UFV);
    __shared__ float2 rk[REGION][HCH];
    for (int idx = tid; idx < REGION * HCH; idx += 256){
        int r = idx >> 6, hh = idx & (HCH - 1);
        int h = h0 + hh;
        float fr = (h < HN / 2) ? (float)h : (float)(h - HN);
        float sv, cv; sincosf(-CC * ((float)r - off0) * fr, &sv, &cv);
        rk[r][hh] = make_float2(cv, sv);
    }
    __syncthreads();
    cplx a0[8], a1[8];
    #pragma unroll
    for (int u = 0; u < 8; ++u){ a0[u] = make_float2(0.f,0.f); a1[u] = make_float2(0.f,0.f); }
    const cplx* pc = P + ((size_t)b * HN + h0) * WN + w;
    for (int hh = 0; hh < HCH; hh += 8){
        float4 pv[8];
        #pragma unroll
        for (int k = 0; k < 8; ++k)
            pv[k] = *(const float4*)(pc + (size_t)(hh + k) * WN);
        #pragma unroll
        for (int k = 0; k < 8; ++k){
            cplx p0 = make_float2(pv[k].x, -pv[k].y);
            cplx p1 = make_float2(pv[k].z, -pv[k].w);
            #pragma unroll
            for (int u = 0; u < 8; ++u){
                int r = rbase * 8 + u;
                if (r < REGION){
                    cplx wv = rk[r][hh + k];
                    a0[u] = cadd(a0[u], cmul(wv, p0));
                    a1[u] = cadd(a1[u], cmul(wv, p1));
                }
            }
        }
    }
    #pragma unroll
    for (int u = 0; u < 8; ++u){
        int r = rbase * 8 + u;
        if (r < REGION){
            cplx* dst = Tpart + (((size_t)hs * BN + b) * REGION + r) * WN + w;
            dst[0] = a0[u]; dst[1] = a1[u];
        }
    }
}

// Deterministic sum of the HS partials. grid (BN*REGION*WN/256), block 256.
__global__ void reduce_T(const cplx* __restrict__ Tpart, cplx* __restrict__ T){
    const size_t STRIDE = (size_t)BN * REGION * WN;
    size_t i = (size_t)blockIdx.x * 256 + threadIdx.x;
    cplx s = make_float2(0.f, 0.f);
    #pragma unroll
    for (int hs = 0; hs < HS; ++hs) s = cadd(s, Tpart[(size_t)hs * STRIDE + i]);
    T[i] = s;
}

// U = T @ col_k, argmax |U|^2, final shifts. grid (BN), block 256.
__global__ void upsample_final(const cplx* __restrict__ Tb, const float* __restrict__ small,
                               float* __restrict__ out){
    const int b = blockIdx.x;
    const int tid = threadIdx.x;
    const float off1 = small[b * 4 + 3];
    const float CC = TWO_PI / (WN * UFV);
    __shared__ float2 ck[128][REGION];
    __shared__ float2 Ts[REGION][128];
    cplx acc[4];
    #pragma unroll
    for (int q = 0; q < 4; ++q) acc[q] = make_float2(0.f, 0.f);
    for (int w0 = 0; w0 < WN; w0 += 128){
        __syncthreads();
        for (int idx = tid; idx < 128 * REGION; idx += 256){
            int ww = idx / REGION, c = idx - ww * REGION;
            int w = w0 + ww;
            float fw = (w < WN / 2) ? (float)w : (float)(w - WN);
            float sv, cv; sincosf(-CC * fw * ((float)c - off1), &sv, &cv);
            ck[ww][c] = make_float2(cv, sv);
        }
        for (int idx = tid; idx < REGION * 128; idx += 256){
            int r = idx >> 7, ww = idx & 127;
            Ts[r][ww] = Tb[((size_t)b * REGION + r) * WN + w0 + ww];
        }
        __syncthreads();
        #pragma unroll
        for (int q = 0; q < 4; ++q){
            int o = tid + 256 * q;
            if (o < REGION * REGION){
                int r = o / REGION, c = o - r * REGION;
                for (int ww = 0; ww < 128; ++ww)
                    acc[q] = cadd(acc[q], cmul(Ts[r][ww], ck[ww][c]));
            }
        }
    }
    float best = -1.0f; int bidx = 0x7fffffff;
    #pragma unroll
    for (int q = 0; q < 4; ++q){
        int o = tid + 256 * q;
        if (o < REGION * REGION){
            float m = acc[q].x * acc[q].x + acc[q].y * acc[q].y;
            if (m > best){ best = m; bidx = o; }
        }
    }
    __shared__ float vals[256];
    __shared__ int   idxs[256];
    vals[tid] = best; idxs[tid] = bidx;
    __syncthreads();
    for (int s = 128; s > 0; s >>= 1){
        if (tid < s){
            if (vals[tid + s] > vals[tid] ||
                (vals[tid + s] == vals[tid] && idxs[tid + s] < idxs[tid])){
                vals[tid] = vals[tid + s]; idxs[tid] = idxs[tid + s];
            }
        }
        __syncthreads();
    }
    if (tid == 0){
        int o = idxs[0];
        float r = (float)(o / REGION) - DFTSHIFT;
        float c = (float)(o % REGION) - DFTSHIFT;
        out[b * 2 + 0] = small[b * 4 + 0] + r / UFV;
        out[b * 2 + 1] = small[b * 4 + 1] + c / UFV;
    }
}

extern "C" void kernel_launch(void* const* d_in, const int* in_sizes, int n_in,
                              void* d_out, int out_size, void* d_ws, size_t ws_size,
                              hipStream_t stream){
    const float* tgt = (const float*)d_in[0];
    const float* src = (const float*)d_in[1];
    float* out = (float*)d_out;

    const size_t BIG = (size_t)BN * HN * WN;      // 8,388,608 complex = 67 MB
    cplx* buf1 = (cplx*)d_ws;                     // F_z -> P (image_product)
    cplx* buf2 = buf1 + BIG;                      // cc rows -> Tpart/T
    float* small = (float*)(buf2 + BIG);
    float2* cand = (float2*)(small + 128);

    const size_t TSTRIDE = (size_t)BN * REGION * WN;
    cplx* Tpart = buf2;
    cplx* T     = buf2 + HS * TSTRIDE;

    dim3 blk(256);
    row_fft_pack<<<dim3(BN * HN), blk, 0, stream>>>(tgt, src, buf1);
    col_fft_fwd<<<dim3(WN / 8, BN), blk, 0, stream>>>(buf1);
    cross_rowinv_pair<<<dim3(HN / 2 + 1, BN), blk, 0, stream>>>(buf1, buf2);
    colinv_argmax<<<dim3(WN / 8, BN), blk, 0, stream>>>(buf2, cand);
    coarse_reduce<<<dim3(BN), dim3(64), 0, stream>>>(cand, small);
    upsample_T<<<dim3(WN / 128, BN, HS), blk, 0, stream>>>(buf1, small, Tpart);
    reduce_T<<<dim3((unsigned)(TSTRIDE / 256)), blk, 0, stream>>>(Tpart, T);
    upsample_final<<<dim3(BN), blk, 0, stream>>>(T, small, out);
}

// Round 5
// 264.879 us; speedup vs baseline: 3.6533x; 1.2633x over previous
//
#include <hip/hip_runtime.h>
#include <math.h>

#define BN 32
#define HN 512
#define WN 512
#define REGION 30
#define UFV 20.0f
#define DFTSHIFT 15.0f
#define TWO_PI 6.2831853071795864769f
#define HS 8              // h-chunks for upsample_T partials
#define HCH (HN / HS)     // 64
#define WS 8              // w-chunks for upsample_U partials
#define WCH (WN / WS)     // 64

typedef float2 cplx;

__device__ __forceinline__ cplx cmul(cplx a, cplx b){
    return make_float2(a.x*b.x - a.y*b.y, a.x*b.y + a.y*b.x);
}
__device__ __forceinline__ cplx cadd(cplx a, cplx b){
    return make_float2(a.x + b.x, a.y + b.y);
}
__device__ __forceinline__ int brev9(int i){ return (int)(__brev((unsigned)i) >> 23); }
// 1D row-FFT LDS swizzle: spreads stride-2^st butterfly patterns to the 4-way float2 floor
__device__ __forceinline__ int swz(int i){ return i + (i >> 4); }        // needs 544 slots
// col-FFT LDS swizzle: 9 coprime to 16 spreads rows; XOR spreads the 8-col group
__device__ __forceinline__ int cswz(int h, int c){ return 9 * h + (c ^ (h & 7)); }

// in-LDS 512-pt radix-2 DIT FFT (swizzled layout), 256 threads, data pre-bit-reversed
__device__ __forceinline__ void fft512_swz(cplx* sm, const float2* tw, int tid){
    #pragma unroll
    for (int st = 1; st <= 9; ++st){
        const int m = 1 << st, half = m >> 1;
        const int j  = tid & (half - 1);
        const int i0 = ((tid >> (st - 1)) << st) + j, i1 = i0 + half;
        cplx w = tw[j << (9 - st)];
        const int a0 = swz(i0), a1 = swz(i1);
        cplx a = sm[a0];
        cplx t = cmul(w, sm[a1]);
        sm[a0] = make_float2(a.x + t.x, a.y + t.y);
        sm[a1] = make_float2(a.x - t.x, a.y - t.y);
        __syncthreads();
    }
}

// Packed row FFT: F_z rows of z = tgt + i*src. grid (BN*HN), block 256.
__global__ void row_fft_pack(const float* __restrict__ tgt, const float* __restrict__ src,
                             cplx* __restrict__ Fz){
    const int rid = blockIdx.x;
    __shared__ cplx sm[544];
    __shared__ float2 tw[256];
    const int tid = threadIdx.x;
    { float sv, cv; sincosf(-TWO_PI * (float)tid * (1.0f/512.0f), &sv, &cv);
      tw[tid] = make_float2(cv, sv); }
    const float* tr = tgt + (size_t)rid * WN;
    const float* sr = src + (size_t)rid * WN;
    #pragma unroll
    for (int u = 0; u < 2; ++u){
        int i = tid + u * 256;
        sm[swz(brev9(i))] = make_float2(tr[i], sr[i]);
    }
    __syncthreads();
    fft512_swz(sm, tw, tid);
    cplx* orow = Fz + (size_t)rid * WN;
    #pragma unroll
    for (int u = 0; u < 2; ++u){ int i = tid + u * 256; orow[i] = sm[swz(i)]; }
}

// Column-wise forward FFT of F_z, 8 cols/block, in place. grid (WN/8, BN).
__global__ void col_fft_fwd(cplx* __restrict__ buf){
    const int b  = blockIdx.y;
    const int w0 = blockIdx.x * 8;
    const int tid = threadIdx.x;
    __shared__ cplx sm[4608];
    __shared__ float2 tw[256];
    { float sv, cv; sincosf(-TWO_PI * (float)tid * (1.0f/512.0f), &sv, &cv);
      tw[tid] = make_float2(cv, sv); }
    cplx* base = buf + (size_t)b * HN * WN + w0;
    for (int idx = tid; idx < HN * 8; idx += 256){
        int h = idx >> 3, c = idx & 7;
        sm[cswz(brev9(h), c)] = base[(size_t)h * WN + c];
    }
    __syncthreads();
    for (int st = 1; st <= 9; ++st){
        const int m = 1 << st, half = m >> 1;
        for (int t2 = tid; t2 < 256 * 8; t2 += 256){
            int c = t2 & 7, k = t2 >> 3;
            int j = k & (half - 1);
            int i0 = ((k >> (st - 1)) << st) + j, i1 = i0 + half;
            cplx w  = tw[j << (9 - st)];
            const int a0 = cswz(i0, c), a1 = cswz(i1, c);
            cplx a  = sm[a0];
            cplx tt = cmul(w, sm[a1]);
            sm[a0] = make_float2(a.x + tt.x, a.y + tt.y);
            sm[a1] = make_float2(a.x - tt.x, a.y - tt.y);
        }
        __syncthreads();
    }
    for (int idx = tid; idx < HN * 8; idx += 256){
        int h = idx >> 3, c = idx & 7;
        base[(size_t)h * WN + c] = sm[cswz(h, c)];
    }
}

// Hermitian unpack + cross-power + row-wise inverse FFT, paired rows (h, N-h).
// grid (257, BN), block 256. P written in place over Fz; cc rows to cc.
__global__ void cross_rowinv_pair(cplx* __restrict__ Fz, cplx* __restrict__ cc){
    const int j = blockIdx.x, b = blockIdx.y;
    const int h1 = j, h2 = (HN - j) & (HN - 1);
    const int tid = threadIdx.x;
    __shared__ cplx sa[544], sb[544];
    __shared__ float2 tw[256];
    { float sv, cv; sincosf(TWO_PI * (float)tid * (1.0f/512.0f), &sv, &cv);
      tw[tid] = make_float2(cv, sv); }
    cplx* r1 = Fz + ((size_t)b * HN + h1) * WN;
    cplx* r2 = Fz + ((size_t)b * HN + h2) * WN;
    #pragma unroll
    for (int u = 0; u < 2; ++u){
        int i = tid + u * 256;
        sa[i] = r1[i]; sb[i] = r2[i];
    }
    __syncthreads();
    // P(k) = -i*(A-B)*conj(A+B)/4,  A = Fz(k), B = conj(Fz(-k))
    cplx P1[2], P2[2];
    #pragma unroll
    for (int u = 0; u < 2; ++u){
        int w  = tid + u * 256;
        int wN = (WN - w) & (WN - 1);
        { cplx A = sa[w];
          cplx B = sb[wN]; B.y = -B.y;
          cplx s = make_float2(A.x + B.x, A.y + B.y);
          cplx d = make_float2(A.x - B.x, A.y - B.y);
          cplx D = make_float2(d.x*s.x + d.y*s.y, d.y*s.x - d.x*s.y);  // d*conj(s)
          P1[u] = make_float2(0.25f * D.y, -0.25f * D.x); }
        { cplx A = sb[w];
          cplx B = sa[wN]; B.y = -B.y;
          cplx s = make_float2(A.x + B.x, A.y + B.y);
          cplx d = make_float2(A.x - B.x, A.y - B.y);
          cplx D = make_float2(d.x*s.x + d.y*s.y, d.y*s.x - d.x*s.y);
          P2[u] = make_float2(0.25f * D.y, -0.25f * D.x); }
    }
    __syncthreads();
    #pragma unroll
    for (int u = 0; u < 2; ++u){
        int w = tid + u * 256;
        r1[w] = P1[u];                     // in-place safe: block owns rows h1,h2
        r2[w] = P2[u];
        sa[swz(brev9(w))] = P1[u];
        sb[swz(brev9(w))] = P2[u];
    }
    __syncthreads();
    #pragma unroll
    for (int st = 1; st <= 9; ++st){       // dual inverse FFT
        const int m = 1 << st, half = m >> 1;
        const int jj = tid & (half - 1);
        const int i0 = ((tid >> (st - 1)) << st) + jj, i1 = i0 + half;
        cplx w = tw[jj << (9 - st)];
        const int a0 = swz(i0), a1 = swz(i1);
        cplx x0 = sa[a0], x1 = cmul(w, sa[a1]);
        sa[a0] = make_float2(x0.x + x1.x, x0.y + x1.y);
        sa[a1] = make_float2(x0.x - x1.x, x0.y - x1.y);
        cplx y0 = sb[a0], y1 = cmul(w, sb[a1]);
        sb[a0] = make_float2(y0.x + y1.x, y0.y + y1.y);
        sb[a1] = make_float2(y0.x - y1.x, y0.y - y1.y);
        __syncthreads();
    }
    cplx* c1 = cc + ((size_t)b * HN + h1) * WN;
    cplx* c2 = cc + ((size_t)b * HN + h2) * WN;
    #pragma unroll
    for (int u = 0; u < 2; ++u){
        int i = tid + u * 256;
        c1[i] = sa[swz(i)];
        c2[i] = sb[swz(i)];
    }
}

// Column-wise inverse FFT + per-block argmax of |cc|^2 (no global writeback).
// grid (WN/8, BN), block 256. cand[b*64+bx] = (maxval, bitcast idx).
__global__ void colinv_argmax(const cplx* __restrict__ buf, float2* __restrict__ cand){
    const int b  = blockIdx.y;
    const int w0 = blockIdx.x * 8;
    const int tid = threadIdx.x;
    __shared__ cplx sm[4608];
    __shared__ float2 tw[256];
    { float sv, cv; sincosf(TWO_PI * (float)tid * (1.0f/512.0f), &sv, &cv);
      tw[tid] = make_float2(cv, sv); }
    const cplx* base = buf + (size_t)b * HN * WN + w0;
    for (int idx = tid; idx < HN * 8; idx += 256){
        int h = idx >> 3, c = idx & 7;
        sm[cswz(brev9(h), c)] = base[(size_t)h * WN + c];
    }
    __syncthreads();
    for (int st = 1; st <= 9; ++st){
        const int m = 1 << st, half = m >> 1;
        for (int t2 = tid; t2 < 256 * 8; t2 += 256){
            int c = t2 & 7, k = t2 >> 3;
            int j = k & (half - 1);
            int i0 = ((k >> (st - 1)) << st) + j, i1 = i0 + half;
            cplx w  = tw[j << (9 - st)];
            const int a0 = cswz(i0, c), a1 = cswz(i1, c);
            cplx a  = sm[a0];
            cplx tt = cmul(w, sm[a1]);
            sm[a0] = make_float2(a.x + tt.x, a.y + tt.y);
            sm[a1] = make_float2(a.x - tt.x, a.y - tt.y);
        }
        __syncthreads();
    }
    float best = -1.0f; int bidx = 0x7fffffff;
    for (int idx = tid; idx < HN * 8; idx += 256){
        int h = idx >> 3, c = idx & 7;
        cplx v = sm[cswz(h, c)];
        float mm = v.x * v.x + v.y * v.y;
        if (mm > best){ best = mm; bidx = h * WN + w0 + c; }
    }
    __shared__ float vals[256];
    __shared__ int   idxs[256];
    vals[tid] = best; idxs[tid] = bidx;
    __syncthreads();
    for (int s = 128; s > 0; s >>= 1){
        if (tid < s){
            if (vals[tid + s] > vals[tid] ||
                (vals[tid + s] == vals[tid] && idxs[tid + s] < idxs[tid])){
                vals[tid] = vals[tid + s]; idxs[tid] = idxs[tid + s];
            }
        }
        __syncthreads();
    }
    if (tid == 0) cand[b * 64 + blockIdx.x] = make_float2(vals[0], __int_as_float(idxs[0]));
}

// Reduce 64 candidates per batch -> coarse shifts + upsample offsets. grid BN, block 64.
__global__ void coarse_reduce(const float2* __restrict__ cand, float* __restrict__ small){
    const int b = blockIdx.x, t = threadIdx.x;
    float2 c = cand[b * 64 + t];
    float v = c.x; int ix = __float_as_int(c.y);
    for (int off = 32; off > 0; off >>= 1){
        float v2 = __shfl_down(v, off);
        int   i2 = __shfl_down(ix, off);
        if (v2 > v || (v2 == v && i2 < ix)){ v = v2; ix = i2; }
    }
    if (t == 0){
        int row = ix / WN, col = ix % WN;
        float sr = (row > HN / 2) ? (float)(row - HN) : (float)row;
        float sc = (col > WN / 2) ? (float)(col - WN) : (float)col;
        small[b * 4 + 0] = sr;
        small[b * 4 + 1] = sc;
        small[b * 4 + 2] = DFTSHIFT - sr * UFV;
        small[b * 4 + 3] = DFTSHIFT - sc * UFV;
    }
}

// Partial T: Tpart[hs][b][r][w] = sum_{h in chunk hs} rk[r][h] * conj(P[b][h][w]).
// grid (WN/128, BN, HS), block 256. Each thread: 2 adjacent w (float4), 8 r values.
__global__ void upsample_T(const cplx* __restrict__ P, const float* __restrict__ small,
                           cplx* __restrict__ Tpart){
    const int b = blockIdx.y, hs = blockIdx.z;
    const int tid = threadIdx.x;
    const int lane = tid & 63;
    const int rbase = tid >> 6;
    const int w = blockIdx.x * 128 + lane * 2;
    const int h0 = hs * HCH;
    const float off0 = small[b * 4 + 2];
    const float CC = TWO_PI / (HN * UFV);
    __shared__ float2 rk[REGION][HCH];
    for (int idx = tid; idx < REGION * HCH; idx += 256){
        int r = idx >> 6, hh = idx & (HCH - 1);
        int h = h0 + hh;
        float fr = (h < HN / 2) ? (float)h : (float)(h - HN);
        float sv, cv; sincosf(-CC * ((float)r - off0) * fr, &sv, &cv);
        rk[r][hh] = make_float2(cv, sv);
    }
    __syncthreads();
    cplx a0[8], a1[8];
    #pragma unroll
    for (int u = 0; u < 8; ++u){ a0[u] = make_float2(0.f,0.f); a1[u] = make_float2(0.f,0.f); }
    const cplx* pc = P + ((size_t)b * HN + h0) * WN + w;
    for (int hh = 0; hh < HCH; hh += 8){
        float4 pv[8];
        #pragma unroll
        for (int k = 0; k < 8; ++k)
            pv[k] = *(const float4*)(pc + (size_t)(hh + k) * WN);
        #pragma unroll
        for (int k = 0; k < 8; ++k){
            cplx p0 = make_float2(pv[k].x, -pv[k].y);
            cplx p1 = make_float2(pv[k].z, -pv[k].w);
            #pragma unroll
            for (int u = 0; u < 8; ++u){
                int r = rbase * 8 + u;
                if (r < REGION){
                    cplx wv = rk[r][hh + k];
                    a0[u] = cadd(a0[u], cmul(wv, p0));
                    a1[u] = cadd(a1[u], cmul(wv, p1));
                }
            }
        }
    }
    #pragma unroll
    for (int u = 0; u < 8; ++u){
        int r = rbase * 8 + u;
        if (r < REGION){
            cplx* dst = Tpart + (((size_t)hs * BN + b) * REGION + r) * WN + w;
            dst[0] = a0[u]; dst[1] = a1[u];
        }
    }
}

// Partial U: Upart[ws][b][o] = sum_{w in chunk ws} T[b][r][w] * ck[w][c], o = r*30+c.
// T is summed on the fly from the HS Tpart partials. grid (WS, BN), block 256.
__global__ void upsample_U_part(const cplx* __restrict__ Tpart, const float* __restrict__ small,
                                cplx* __restrict__ Upart){
    const int ws = blockIdx.x, b = blockIdx.y;
    const int tid = threadIdx.x;
    const int w0 = ws * WCH;
    const float off1 = small[b * 4 + 3];
    const float CC = TWO_PI / (WN * UFV);
    __shared__ float2 Ts[REGION][WCH];     // 15 KB
    __shared__ float2 ck[WCH][REGION];     // 15 KB
    const size_t TS = (size_t)BN * REGION * WN;
    for (int idx = tid; idx < REGION * WCH; idx += 256){
        int r = idx >> 6, ww = idx & (WCH - 1);
        cplx s = make_float2(0.f, 0.f);
        #pragma unroll
        for (int hs = 0; hs < HS; ++hs)
            s = cadd(s, Tpart[(size_t)hs * TS + ((size_t)b * REGION + r) * WN + w0 + ww]);
        Ts[r][ww] = s;
    }
    for (int idx = tid; idx < WCH * REGION; idx += 256){
        int ww = idx / REGION, c = idx - ww * REGION;
        int w = w0 + ww;
        float fw = (w < WN / 2) ? (float)w : (float)(w - WN);
        float sv, cv; sincosf(-CC * fw * ((float)c - off1), &sv, &cv);
        ck[ww][c] = make_float2(cv, sv);
    }
    __syncthreads();
    #pragma unroll
    for (int q = 0; q < 4; ++q){
        int o = tid + 256 * q;
        if (o < REGION * REGION){
            int r = o / REGION, c = o - r * REGION;
            cplx acc = make_float2(0.f, 0.f);
            #pragma unroll
            for (int ww = 0; ww < WCH; ++ww)
                acc = cadd(acc, cmul(Ts[r][ww], ck[ww][c]));
            Upart[((size_t)ws * BN + b) * (REGION * REGION) + o] = acc;
        }
    }
}

// Sum the WS U-partials, argmax |U|^2, final shifts. grid (BN), block 256.
__global__ void upsample_argmax(const cplx* __restrict__ Upart, const float* __restrict__ small,
                                float* __restrict__ out){
    const int b = blockIdx.x;
    const int tid = threadIdx.x;
    float best = -1.0f; int bidx = 0x7fffffff;
    #pragma unroll
    for (int q = 0; q < 4; ++q){
        int o = tid + 256 * q;
        if (o < REGION * REGION){
            cplx u = make_float2(0.f, 0.f);
            #pragma unroll
            for (int ws = 0; ws < WS; ++ws)
                u = cadd(u, Upart[((size_t)ws * BN + b) * (REGION * REGION) + o]);
            float m = u.x * u.x + u.y * u.y;
            if (m > best){ best = m; bidx = o; }
        }
    }
    __shared__ float vals[256];
    __shared__ int   idxs[256];
    vals[tid] = best; idxs[tid] = bidx;
    __syncthreads();
    for (int s = 128; s > 0; s >>= 1){
        if (tid < s){
            if (vals[tid + s] > vals[tid] ||
                (vals[tid + s] == vals[tid] && idxs[tid + s] < idxs[tid])){
                vals[tid] = vals[tid + s]; idxs[tid] = idxs[tid + s];
            }
        }
        __syncthreads();
    }
    if (tid == 0){
        int o = idxs[0];
        float r = (float)(o / REGION) - DFTSHIFT;
        float c = (float)(o % REGION) - DFTSHIFT;
        out[b * 2 + 0] = small[b * 4 + 0] + r / UFV;
        out[b * 2 + 1] = small[b * 4 + 1] + c / UFV;
    }
}

extern "C" void kernel_launch(void* const* d_in, const int* in_sizes, int n_in,
                              void* d_out, int out_size, void* d_ws, size_t ws_size,
                              hipStream_t stream){
    const float* tgt = (const float*)d_in[0];
    const float* src = (const float*)d_in[1];
    float* out = (float*)d_out;

    const size_t BIG = (size_t)BN * HN * WN;      // 8,388,608 complex = 67 MB
    cplx* buf1 = (cplx*)d_ws;                     // F_z -> P (image_product)
    cplx* buf2 = buf1 + BIG;                      // cc rows -> Tpart / Upart
    float* small = (float*)(buf2 + BIG);
    float2* cand = (float2*)(small + 128);

    const size_t TSTRIDE = (size_t)BN * REGION * WN;
    cplx* Tpart = buf2;                                // HS * TSTRIDE = 31.5 MB
    cplx* Upart = buf2 + HS * TSTRIDE;                 // WS*BN*900 = 1.8 MB

    dim3 blk(256);
    row_fft_pack<<<dim3(BN * HN), blk, 0, stream>>>(tgt, src, buf1);
    col_fft_fwd<<<dim3(WN / 8, BN), blk, 0, stream>>>(buf1);
    cross_rowinv_pair<<<dim3(HN / 2 + 1, BN), blk, 0, stream>>>(buf1, buf2);
    colinv_argmax<<<dim3(WN / 8, BN), blk, 0, stream>>>(buf2, cand);
    coarse_reduce<<<dim3(BN), dim3(64), 0, stream>>>(cand, small);
    upsample_T<<<dim3(WN / 128, BN, HS), blk, 0, stream>>>(buf1, small, Tpart);
    upsample_U_part<<<dim3(WS, BN), blk, 0, stream>>>(Tpart, small, Upart);
    upsample_argmax<<<dim3(BN), blk, 0, stream>>>(Upart, small, out);
}

// Round 6
// 241.188 us; speedup vs baseline: 4.0122x; 1.0982x over previous
//
#include <hip/hip_runtime.h>
#include <math.h>

#define BN 32
#define HN 512
#define WN 512
#define REGION 30
#define UFV 20.0f
#define DFTSHIFT 15.0f
#define TWO_PI 6.2831853071795864769f
#define HS 8              // h-chunks for upsample_T partials
#define HCH (HN / HS)     // 64
#define WS 8              // w-chunks for upsample_U partials
#define WCH (WN / WS)     // 64

typedef float2 cplx;

__device__ __forceinline__ cplx cmul(cplx a, cplx b){
    return make_float2(a.x*b.x - a.y*b.y, a.x*b.y + a.y*b.x);
}
__device__ __forceinline__ cplx cadd(cplx a, cplx b){
    return make_float2(a.x + b.x, a.y + b.y);
}
__device__ __forceinline__ int brev9(int i){ return (int)(__brev((unsigned)i) >> 23); }
// col-FFT LDS swizzle: 9 coprime to 16 spreads rows; XOR spreads the 8-col group
__device__ __forceinline__ int cswz(int h, int c){ return 9 * h + (c ^ (h & 7)); }

#define BFLY(a,b,w){ cplx t_ = cmul(w,b); b = make_float2(a.x - t_.x, a.y - t_.y); a = cadd(a, t_); }
#define BFLY1(a,b){ cplx t_ = b; b = make_float2(a.x - t_.x, a.y - t_.y); a = cadd(a, t_); }

// ---- wave-level 512-pt FFT: 64 lanes, 8 elems/lane in registers, radix-2 DIT
// grouped into 3 register phases; LDS scratch (>=576 cplx slots) only for the
// two inter-phase transposes. Computation graph (butterfly order + tw entries)
// is bit-identical to the 9-stage radix-2 loop.
// Input:  v[j] = x[brev9(8*lane+j)]   Output: v[j] = X[64*j + lane]
__device__ __forceinline__ void fft512_regs(cplx* v, const float2* tw, cplx* ds, int lane){
    const cplx wI  = *(const cplx*)&tw[128];   // (0, sign)
    const cplx w8a = *(const cplx*)&tw[64];
    const cplx w8b = *(const cplx*)&tw[192];
    // phase 1: stages 1-3 (distances 1,2,4 over j)
    BFLY1(v[0],v[1]); BFLY1(v[2],v[3]); BFLY1(v[4],v[5]); BFLY1(v[6],v[7]);
    BFLY1(v[0],v[2]); BFLY(v[1],v[3],wI); BFLY1(v[4],v[6]); BFLY(v[5],v[7],wI);
    BFLY1(v[0],v[4]); BFLY(v[1],v[5],w8a); BFLY(v[2],v[6],wI); BFLY(v[3],v[7],w8b);
    // transition 1->2: slot S(i)=i+(i>>3); write S(8l+j)=9l+j, read S(64h+8j+lo)
    const int h = lane >> 3, lo = lane & 7;
    const int bw = 9 * lane;
    const int br = 72 * h + lo;
    #pragma unroll
    for (int j = 0; j < 8; ++j) ds[bw + j] = v[j];
    asm volatile("s_waitcnt lgkmcnt(0)" ::: "memory");
    #pragma unroll
    for (int j = 0; j < 8; ++j) v[j] = ds[br + 9*j];
    // phase 2: stages 4-6 (distances 8,16,32); v[j] = data[64h + 8j + lo]
    {
        cplx wA = *(const cplx*)&tw[lo<<5];
        BFLY(v[0],v[1],wA); BFLY(v[2],v[3],wA); BFLY(v[4],v[5],wA); BFLY(v[6],v[7],wA);
        cplx wB0 = *(const cplx*)&tw[lo<<4], wB1 = *(const cplx*)&tw[128+(lo<<4)];
        BFLY(v[0],v[2],wB0); BFLY(v[1],v[3],wB1); BFLY(v[4],v[6],wB0); BFLY(v[5],v[7],wB1);
        cplx wC0 = *(const cplx*)&tw[lo<<3], wC1 = *(const cplx*)&tw[64+(lo<<3)];
        cplx wC2 = *(const cplx*)&tw[128+(lo<<3)], wC3 = *(const cplx*)&tw[192+(lo<<3)];
        BFLY(v[0],v[4],wC0); BFLY(v[1],v[5],wC1); BFLY(v[2],v[6],wC2); BFLY(v[3],v[7],wC3);
    }
    // transition 2->3: write back S(64h+8j+lo), read S(64j+l)=72j+l+(l>>3)
    #pragma unroll
    for (int j = 0; j < 8; ++j) ds[br + 9*j] = v[j];
    asm volatile("s_waitcnt lgkmcnt(0)" ::: "memory");
    const int br3 = lane + (lane >> 3);
    #pragma unroll
    for (int j = 0; j < 8; ++j) v[j] = ds[br3 + 72*j];
    // phase 3: stages 7-9 (distances 64,128,256); v[j] = data[64j + lane]
    {
        cplx wD = *(const cplx*)&tw[lane<<2];
        BFLY(v[0],v[1],wD); BFLY(v[2],v[3],wD); BFLY(v[4],v[5],wD); BFLY(v[6],v[7],wD);
        cplx wE0 = *(const cplx*)&tw[lane<<1], wE1 = *(const cplx*)&tw[128+(lane<<1)];
        BFLY(v[0],v[2],wE0); BFLY(v[1],v[3],wE1); BFLY(v[4],v[6],wE0); BFLY(v[5],v[7],wE1);
        cplx wF0 = *(const cplx*)&tw[lane], wF1 = *(const cplx*)&tw[64+lane];
        cplx wF2 = *(const cplx*)&tw[128+lane], wF3 = *(const cplx*)&tw[192+lane];
        BFLY(v[0],v[4],wF0); BFLY(v[1],v[5],wF1); BFLY(v[2],v[6],wF2); BFLY(v[3],v[7],wF3);
    }
}

// Packed row FFT: F_z rows of z = tgt + i*src. Wave-per-row. grid (BN*HN/4), block 256.
__global__ void __launch_bounds__(256) row_fft_pack(const float* __restrict__ tgt,
                                                    const float* __restrict__ src,
                                                    cplx* __restrict__ Fz){
    __shared__ float2 tw[256];
    __shared__ cplx ds[4 * 576];
    const int tid = threadIdx.x;
    { float sv, cv; sincosf(-TWO_PI * (float)tid * (1.0f/512.0f), &sv, &cv);
      tw[tid] = make_float2(cv, sv); }
    __syncthreads();
    const int wave = tid >> 6, lane = tid & 63;
    const int rid = blockIdx.x * 4 + wave;
    const float* tr = tgt + (size_t)rid * WN;
    const float* sr = src + (size_t)rid * WN;
    const int rb6 = (int)(__brev((unsigned)lane) >> 26);   // brev6(lane)
    const int B3[8] = {0,256,128,384,64,320,192,448};      // brev3(j)*64
    cplx v[8];
    #pragma unroll
    for (int j = 0; j < 8; ++j){ int o = B3[j] + rb6; v[j] = make_float2(tr[o], sr[o]); }
    fft512_regs(v, (const float2*)tw, ds + wave * 576, lane);
    cplx* orow = Fz + (size_t)rid * WN;
    #pragma unroll
    for (int j = 0; j < 8; ++j) orow[64*j + lane] = v[j];
}

// Column-wise forward FFT of F_z, 8 cols/block, in place. grid (WN/8, BN).
__global__ void col_fft_fwd(cplx* __restrict__ buf){
    const int b  = blockIdx.y;
    const int w0 = blockIdx.x * 8;
    const int tid = threadIdx.x;
    __shared__ cplx sm[4608];
    __shared__ float2 tw[256];
    { float sv, cv; sincosf(-TWO_PI * (float)tid * (1.0f/512.0f), &sv, &cv);
      tw[tid] = make_float2(cv, sv); }
    cplx* base = buf + (size_t)b * HN * WN + w0;
    for (int idx = tid; idx < HN * 8; idx += 256){
        int h = idx >> 3, c = idx & 7;
        sm[cswz(brev9(h), c)] = base[(size_t)h * WN + c];
    }
    __syncthreads();
    for (int st = 1; st <= 9; ++st){
        const int half = 1 << (st - 1);
        for (int t2 = tid; t2 < 256 * 8; t2 += 256){
            int c = t2 & 7, k = t2 >> 3;
            int j = k & (half - 1);
            int i0 = ((k >> (st - 1)) << st) + j, i1 = i0 + half;
            cplx w  = tw[j << (9 - st)];
            const int a0 = cswz(i0, c), a1 = cswz(i1, c);
            cplx a  = sm[a0];
            cplx tt = cmul(w, sm[a1]);
            sm[a0] = make_float2(a.x + tt.x, a.y + tt.y);
            sm[a1] = make_float2(a.x - tt.x, a.y - tt.y);
        }
        __syncthreads();
    }
    for (int idx = tid; idx < HN * 8; idx += 256){
        int h = idx >> 3, c = idx & 7;
        base[(size_t)h * WN + c] = sm[cswz(h, c)];
    }
}

// Hermitian unpack + cross-power + dual row-wise inverse FFT. Wave-per-row-pair.
// grid (65, BN), block 256. P written in place over Fz; cc rows written out.
__global__ void __launch_bounds__(256) cross_rowinv(cplx* __restrict__ Fz, cplx* __restrict__ cc){
    __shared__ float2 tw[256];
    __shared__ cplx ds[4 * 1184];
    const int tid = threadIdx.x;
    { float sv, cv; sincosf(TWO_PI * (float)tid * (1.0f/512.0f), &sv, &cv);
      tw[tid] = make_float2(cv, sv); }
    __syncthreads();
    const int wave = tid >> 6, lane = tid & 63;
    const int p = blockIdx.x * 4 + wave;
    if (p > 256) return;
    const int b = blockIdx.y;
    const int h1 = p, h2 = (HN - p) & (HN - 1);
    cplx* r1 = Fz + ((size_t)b * HN + h1) * WN;
    cplx* r2 = Fz + ((size_t)b * HN + h2) * WN;
    cplx* A = ds + wave * 1184;
    cplx* B = A + 592;
    #pragma unroll
    for (int u = 0; u < 8; ++u){
        A[lane + 64*u] = r1[lane + 64*u];
        B[lane + 64*u] = r2[lane + 64*u];
    }
    asm volatile("s_waitcnt lgkmcnt(0)" ::: "memory");
    const int rb6 = (int)(__brev((unsigned)lane) >> 26);
    const int B3[8] = {0,256,128,384,64,320,192,448};
    cplx v1[8], v2[8];
    #pragma unroll
    for (int j = 0; j < 8; ++j){
        int w  = B3[j] + rb6;
        int wm = (WN - w) & (WN - 1);
        cplx Aw = A[w], Bw = B[w], Am = A[wm], Bm = B[wm];
        // P(k) = -i*(X - conj(Y))*conj(X + conj(Y))/4
        { cplx Bc = make_float2(Bm.x, -Bm.y);
          cplx s = cadd(Aw, Bc);
          cplx d = make_float2(Aw.x - Bc.x, Aw.y - Bc.y);
          cplx D = make_float2(d.x*s.x + d.y*s.y, d.y*s.x - d.x*s.y);
          v1[j] = make_float2(0.25f * D.y, -0.25f * D.x); }
        { cplx Ac = make_float2(Am.x, -Am.y);
          cplx s = cadd(Bw, Ac);
          cplx d = make_float2(Bw.x - Ac.x, Bw.y - Ac.y);
          cplx D = make_float2(d.x*s.x + d.y*s.y, d.y*s.x - d.x*s.y);
          v2[j] = make_float2(0.25f * D.y, -0.25f * D.x); }
        r1[w] = v1[j];   // P writeback (rows owned exclusively by this wave)
        r2[w] = v2[j];
    }
    // v1/v2 are already in phase-1 register order (index brev9(8*lane+j))
    fft512_regs(v1, (const float2*)tw, A, lane);
    fft512_regs(v2, (const float2*)tw, B, lane);
    cplx* c1 = cc + ((size_t)b * HN + h1) * WN;
    cplx* c2 = cc + ((size_t)b * HN + h2) * WN;
    #pragma unroll
    for (int j = 0; j < 8; ++j){ c1[64*j + lane] = v1[j]; c2[64*j + lane] = v2[j]; }
}

// Column-wise inverse FFT + per-block argmax of |cc|^2 (no global writeback).
// grid (WN/8, BN), block 256. cand[b*64+bx] = (maxval, bitcast idx).
__global__ void colinv_argmax(const cplx* __restrict__ buf, float2* __restrict__ cand){
    const int b  = blockIdx.y;
    const int w0 = blockIdx.x * 8;
    const int tid = threadIdx.x;
    __shared__ cplx sm[4608];
    __shared__ float2 tw[256];
    { float sv, cv; sincosf(TWO_PI * (float)tid * (1.0f/512.0f), &sv, &cv);
      tw[tid] = make_float2(cv, sv); }
    const cplx* base = buf + (size_t)b * HN * WN + w0;
    for (int idx = tid; idx < HN * 8; idx += 256){
        int h = idx >> 3, c = idx & 7;
        sm[cswz(brev9(h), c)] = base[(size_t)h * WN + c];
    }
    __syncthreads();
    for (int st = 1; st <= 9; ++st){
        const int half = 1 << (st - 1);
        for (int t2 = tid; t2 < 256 * 8; t2 += 256){
            int c = t2 & 7, k = t2 >> 3;
            int j = k & (half - 1);
            int i0 = ((k >> (st - 1)) << st) + j, i1 = i0 + half;
            cplx w  = tw[j << (9 - st)];
            const int a0 = cswz(i0, c), a1 = cswz(i1, c);
            cplx a  = sm[a0];
            cplx tt = cmul(w, sm[a1]);
            sm[a0] = make_float2(a.x + tt.x, a.y + tt.y);
            sm[a1] = make_float2(a.x - tt.x, a.y - tt.y);
        }
        __syncthreads();
    }
    float best = -1.0f; int bidx = 0x7fffffff;
    for (int idx = tid; idx < HN * 8; idx += 256){
        int h = idx >> 3, c = idx & 7;
        cplx v = sm[cswz(h, c)];
        float mm = v.x * v.x + v.y * v.y;
        if (mm > best){ best = mm; bidx = h * WN + w0 + c; }
    }
    __shared__ float vals[256];
    __shared__ int   idxs[256];
    vals[tid] = best; idxs[tid] = bidx;
    __syncthreads();
    for (int s = 128; s > 0; s >>= 1){
        if (tid < s){
            if (vals[tid + s] > vals[tid] ||
                (vals[tid + s] == vals[tid] && idxs[tid + s] < idxs[tid])){
                vals[tid] = vals[tid + s]; idxs[tid] = idxs[tid + s];
            }
        }
        __syncthreads();
    }
    if (tid == 0) cand[b * 64 + blockIdx.x] = make_float2(vals[0], __int_as_float(idxs[0]));
}

// Reduce 64 candidates per batch -> coarse shifts + upsample offsets. grid BN, block 64.
__global__ void coarse_reduce(const float2* __restrict__ cand, float* __restrict__ small){
    const int b = blockIdx.x, t = threadIdx.x;
    float2 c = cand[b * 64 + t];
    float v = c.x; int ix = __float_as_int(c.y);
    for (int off = 32; off > 0; off >>= 1){
        float v2 = __shfl_down(v, off);
        int   i2 = __shfl_down(ix, off);
        if (v2 > v || (v2 == v && i2 < ix)){ v = v2; ix = i2; }
    }
    if (t == 0){
        int row = ix / WN, col = ix % WN;
        float sr = (row > HN / 2) ? (float)(row - HN) : (float)row;
        float sc = (col > WN / 2) ? (float)(col - WN) : (float)col;
        small[b * 4 + 0] = sr;
        small[b * 4 + 1] = sc;
        small[b * 4 + 2] = DFTSHIFT - sr * UFV;
        small[b * 4 + 3] = DFTSHIFT - sc * UFV;
    }
}

// Partial T: Tpart[hs][b][r][w] = sum_{h in chunk hs} rk[r][h] * conj(P[b][h][w]).
// grid (WN/64, BN, HS) = 2048 blocks, block 256 = 8 r-groups x 32 w-pairs.
__global__ void __launch_bounds__(256) upsample_T(const cplx* __restrict__ P,
                                                  const float* __restrict__ small,
                                                  cplx* __restrict__ Tpart){
    const int b = blockIdx.y, hs = blockIdx.z;
    const int tid = threadIdx.x;
    const int wp = tid & 31;              // w-pair
    const int rbase = tid >> 5;           // 0..7, 4 r each
    const int w = blockIdx.x * 64 + wp * 2;
    const int h0 = hs * HCH;
    const float off0 = small[b * 4 + 2];
    const float CC = TWO_PI / (HN * UFV);
    __shared__ float2 rk[REGION][HCH];
    for (int idx = tid; idx < REGION * HCH; idx += 256){
        int r = idx >> 6, hh = idx & (HCH - 1);
        int h = h0 + hh;
        float fr = (h < HN / 2) ? (float)h : (float)(h - HN);
        float sv, cv; sincosf(-CC * ((float)r - off0) * fr, &sv, &cv);
        rk[r][hh] = make_float2(cv, sv);
    }
    __syncthreads();
    cplx a0[4], a1[4];
    #pragma unroll
    for (int u = 0; u < 4; ++u){ a0[u] = make_float2(0.f,0.f); a1[u] = make_float2(0.f,0.f); }
    const cplx* pc = P + ((size_t)b * HN + h0) * WN + w;
    for (int hh = 0; hh < HCH; hh += 8){
        float4 pv[8];
        #pragma unroll
        for (int k = 0; k < 8; ++k)
            pv[k] = *(const float4*)(pc + (size_t)(hh + k) * WN);
        #pragma unroll
        for (int k = 0; k < 8; ++k){
            cplx p0 = make_float2(pv[k].x, -pv[k].y);   // conj(P)
            cplx p1 = make_float2(pv[k].z, -pv[k].w);
            #pragma unroll
            for (int u = 0; u < 4; ++u){
                int r = rbase * 4 + u;
                if (r < REGION){
                    cplx wv = rk[r][hh + k];
                    a0[u] = cadd(a0[u], cmul(wv, p0));
                    a1[u] = cadd(a1[u], cmul(wv, p1));
                }
            }
        }
    }
    #pragma unroll
    for (int u = 0; u < 4; ++u){
        int r = rbase * 4 + u;
        if (r < REGION){
            float4* dst = (float4*)(Tpart + (((size_t)hs * BN + b) * REGION + r) * WN + w);
            *dst = make_float4(a0[u].x, a0[u].y, a1[u].x, a1[u].y);
        }
    }
}

// Partial U: Upart[ws][b][o] = sum_{w in chunk ws} T[b][r][w] * ck[w][c], o = r*30+c.
// T summed on the fly from the HS Tpart partials. grid (WS, BN), block 256.
__global__ void upsample_U_part(const cplx* __restrict__ Tpart, const float* __restrict__ small,
                                cplx* __restrict__ Upart){
    const int ws = blockIdx.x, b = blockIdx.y;
    const int tid = threadIdx.x;
    const int w0 = ws * WCH;
    const float off1 = small[b * 4 + 3];
    const float CC = TWO_PI / (WN * UFV);
    __shared__ float2 Ts[REGION][WCH];
    __shared__ float2 ck[WCH][REGION];
    const size_t TS = (size_t)BN * REGION * WN;
    for (int idx = tid; idx < REGION * WCH; idx += 256){
        int r = idx >> 6, ww = idx & (WCH - 1);
        cplx s = make_float2(0.f, 0.f);
        #pragma unroll
        for (int hs = 0; hs < HS; ++hs)
            s = cadd(s, Tpart[(size_t)hs * TS + ((size_t)b * REGION + r) * WN + w0 + ww]);
        Ts[r][ww] = s;
    }
    for (int idx = tid; idx < WCH * REGION; idx += 256){
        int ww = idx / REGION, c = idx - ww * REGION;
        int w = w0 + ww;
        float fw = (w < WN / 2) ? (float)w : (float)(w - WN);
        float sv, cv; sincosf(-CC * fw * ((float)c - off1), &sv, &cv);
        ck[ww][c] = make_float2(cv, sv);
    }
    __syncthreads();
    #pragma unroll
    for (int q = 0; q < 4; ++q){
        int o = tid + 256 * q;
        if (o < REGION * REGION){
            int r = o / REGION, c = o - r * REGION;
            cplx acc = make_float2(0.f, 0.f);
            #pragma unroll
            for (int ww = 0; ww < WCH; ++ww)
                acc = cadd(acc, cmul(Ts[r][ww], ck[ww][c]));
            Upart[((size_t)ws * BN + b) * (REGION * REGION) + o] = acc;
        }
    }
}

// Sum the WS U-partials, argmax |U|^2, final shifts. grid (BN), block 256.
__global__ void upsample_argmax(const cplx* __restrict__ Upart, const float* __restrict__ small,
                                float* __restrict__ out){
    const int b = blockIdx.x;
    const int tid = threadIdx.x;
    float best = -1.0f; int bidx = 0x7fffffff;
    #pragma unroll
    for (int q = 0; q < 4; ++q){
        int o = tid + 256 * q;
        if (o < REGION * REGION){
            cplx u = make_float2(0.f, 0.f);
            #pragma unroll
            for (int ws = 0; ws < WS; ++ws)
                u = cadd(u, Upart[((size_t)ws * BN + b) * (REGION * REGION) + o]);
            float m = u.x * u.x + u.y * u.y;
            if (m > best){ best = m; bidx = o; }
        }
    }
    __shared__ float vals[256];
    __shared__ int   idxs[256];
    vals[tid] = best; idxs[tid] = bidx;
    __syncthreads();
    for (int s = 128; s > 0; s >>= 1){
        if (tid < s){
            if (vals[tid + s] > vals[tid] ||
                (vals[tid + s] == vals[tid] && idxs[tid + s] < idxs[tid])){
                vals[tid] = vals[tid + s]; idxs[tid] = idxs[tid + s];
            }
        }
        __syncthreads();
    }
    if (tid == 0){
        int o = idxs[0];
        float r = (float)(o / REGION) - DFTSHIFT;
        float c = (float)(o % REGION) - DFTSHIFT;
        out[b * 2 + 0] = small[b * 4 + 0] + r / UFV;
        out[b * 2 + 1] = small[b * 4 + 1] + c / UFV;
    }
}

extern "C" void kernel_launch(void* const* d_in, const int* in_sizes, int n_in,
                              void* d_out, int out_size, void* d_ws, size_t ws_size,
                              hipStream_t stream){
    const float* tgt = (const float*)d_in[0];
    const float* src = (const float*)d_in[1];
    float* out = (float*)d_out;

    const size_t BIG = (size_t)BN * HN * WN;      // 8,388,608 complex = 67 MB
    cplx* buf1 = (cplx*)d_ws;                     // F_z -> P (image_product)
    cplx* buf2 = buf1 + BIG;                      // cc rows -> Tpart / Upart
    float* small = (float*)(buf2 + BIG);
    float2* cand = (float2*)(small + 128);

    const size_t TSTRIDE = (size_t)BN * REGION * WN;
    cplx* Tpart = buf2;                                // HS * TSTRIDE = 31.5 MB
    cplx* Upart = buf2 + HS * TSTRIDE;                 // WS*BN*900 = 1.8 MB

    dim3 blk(256);
    row_fft_pack<<<dim3(BN * HN / 4), blk, 0, stream>>>(tgt, src, buf1);
    col_fft_fwd<<<dim3(WN / 8, BN), blk, 0, stream>>>(buf1);
    cross_rowinv<<<dim3((257 + 3) / 4, BN), blk, 0, stream>>>(buf1, buf2);
    colinv_argmax<<<dim3(WN / 8, BN), blk, 0, stream>>>(buf2, cand);
    coarse_reduce<<<dim3(BN), dim3(64), 0, stream>>>(cand, small);
    upsample_T<<<dim3(WN / 64, BN, HS), blk, 0, stream>>>(buf1, small, Tpart);
    upsample_U_part<<<dim3(WS, BN), blk, 0, stream>>>(Tpart, small, Upart);
    upsample_argmax<<<dim3(BN), blk, 0, stream>>>(Upart, small, out);
}

// Round 7
// 220.724 us; speedup vs baseline: 4.3841x; 1.0927x over previous
//
#include <hip/hip_runtime.h>
#include <math.h>

#define BN 32
#define HN 512
#define WN 512
#define REGION 30
#define RPAD 32
#define UFV 20.0f
#define DFTSHIFT 15.0f
#define TWO_PI 6.2831853071795864769f
#define HS 8              // h-chunks for upsample_T partials
#define HCH (HN / HS)     // 64
#define WS 8              // w-chunks for upsample_U partials
#define WCH (WN / WS)     // 64

typedef float2 cplx;

__device__ __forceinline__ cplx cmul(cplx a, cplx b){
    return make_float2(a.x*b.x - a.y*b.y, a.x*b.y + a.y*b.x);
}
__device__ __forceinline__ cplx cadd(cplx a, cplx b){
    return make_float2(a.x + b.x, a.y + b.y);
}
__device__ __forceinline__ cplx csub(cplx a, cplx b){
    return make_float2(a.x - b.x, a.y - b.y);
}
__device__ __forceinline__ int brev9(int i){ return (int)(__brev((unsigned)i) >> 23); }
// col-FFT LDS swizzle: 9 coprime to 16 spreads rows; XOR spreads the 8-col group
__device__ __forceinline__ int cswz(int h, int c){ return 9 * h + (c ^ (h & 7)); }

#define BFLY(a,b,w){ cplx t_ = cmul(w,b); b = make_float2(a.x - t_.x, a.y - t_.y); a = cadd(a, t_); }
#define BFLY1(a,b){ cplx t_ = b; b = make_float2(a.x - t_.x, a.y - t_.y); a = cadd(a, t_); }

// ---- wave-level 512-pt FFT: 64 lanes, 8 elems/lane in registers, radix-2 DIT
// grouped into 3 register phases; LDS scratch (>=576 cplx slots) only for the
// two inter-phase transposes. Computation graph = the 9-stage radix-2 loop.
// Input:  v[j] = x[brev9(8*lane+j)]   Output: v[j] = X[64*j + lane]
__device__ __forceinline__ void fft512_regs(cplx* v, const float2* tw, cplx* ds, int lane){
    const cplx wI  = *(const cplx*)&tw[128];   // (0, sign)
    const cplx w8a = *(const cplx*)&tw[64];
    const cplx w8b = *(const cplx*)&tw[192];
    // phase 1: stages 1-3 (distances 1,2,4 over j)
    BFLY1(v[0],v[1]); BFLY1(v[2],v[3]); BFLY1(v[4],v[5]); BFLY1(v[6],v[7]);
    BFLY1(v[0],v[2]); BFLY(v[1],v[3],wI); BFLY1(v[4],v[6]); BFLY(v[5],v[7],wI);
    BFLY1(v[0],v[4]); BFLY(v[1],v[5],w8a); BFLY(v[2],v[6],wI); BFLY(v[3],v[7],w8b);
    // transition 1->2: slot S(i)=i+(i>>3); write S(8l+j)=9l+j, read S(64h+8j+lo)
    const int h = lane >> 3, lo = lane & 7;
    const int bw = 9 * lane;
    const int br = 72 * h + lo;
    #pragma unroll
    for (int j = 0; j < 8; ++j) ds[bw + j] = v[j];
    asm volatile("s_waitcnt lgkmcnt(0)" ::: "memory");
    #pragma unroll
    for (int j = 0; j < 8; ++j) v[j] = ds[br + 9*j];
    // phase 2: stages 4-6 (distances 8,16,32); v[j] = data[64h + 8j + lo]
    {
        cplx wA = *(const cplx*)&tw[lo<<5];
        BFLY(v[0],v[1],wA); BFLY(v[2],v[3],wA); BFLY(v[4],v[5],wA); BFLY(v[6],v[7],wA);
        cplx wB0 = *(const cplx*)&tw[lo<<4], wB1 = *(const cplx*)&tw[128+(lo<<4)];
        BFLY(v[0],v[2],wB0); BFLY(v[1],v[3],wB1); BFLY(v[4],v[6],wB0); BFLY(v[5],v[7],wB1);
        cplx wC0 = *(const cplx*)&tw[lo<<3], wC1 = *(const cplx*)&tw[64+(lo<<3)];
        cplx wC2 = *(const cplx*)&tw[128+(lo<<3)], wC3 = *(const cplx*)&tw[192+(lo<<3)];
        BFLY(v[0],v[4],wC0); BFLY(v[1],v[5],wC1); BFLY(v[2],v[6],wC2); BFLY(v[3],v[7],wC3);
    }
    // transition 2->3: write back S(64h+8j+lo), read S(64j+l)=72j+l+(l>>3)
    #pragma unroll
    for (int j = 0; j < 8; ++j) ds[br + 9*j] = v[j];
    asm volatile("s_waitcnt lgkmcnt(0)" ::: "memory");
    const int br3 = lane + (lane >> 3);
    #pragma unroll
    for (int j = 0; j < 8; ++j) v[j] = ds[br3 + 72*j];
    // phase 3: stages 7-9 (distances 64,128,256); v[j] = data[64j + lane]
    {
        cplx wD = *(const cplx*)&tw[lane<<2];
        BFLY(v[0],v[1],wD); BFLY(v[2],v[3],wD); BFLY(v[4],v[5],wD); BFLY(v[6],v[7],wD);
        cplx wE0 = *(const cplx*)&tw[lane<<1], wE1 = *(const cplx*)&tw[128+(lane<<1)];
        BFLY(v[0],v[2],wE0); BFLY(v[1],v[3],wE1); BFLY(v[4],v[6],wE0); BFLY(v[5],v[7],wE1);
        cplx wF0 = *(const cplx*)&tw[lane], wF1 = *(const cplx*)&tw[64+lane];
        cplx wF2 = *(const cplx*)&tw[128+lane], wF3 = *(const cplx*)&tw[192+lane];
        BFLY(v[0],v[4],wF0); BFLY(v[1],v[5],wF1); BFLY(v[2],v[6],wF2); BFLY(v[3],v[7],wF3);
    }
}

// Packed row FFT: F_z rows of z = tgt + i*src. Wave-per-row. grid (BN*HN/4), block 256.
__global__ void __launch_bounds__(256) row_fft_pack(const float* __restrict__ tgt,
                                                    const float* __restrict__ src,
                                                    cplx* __restrict__ Fz){
    __shared__ float2 tw[256];
    __shared__ cplx ds[4 * 576];
    const int tid = threadIdx.x;
    { float sv, cv; sincosf(-TWO_PI * (float)tid * (1.0f/512.0f), &sv, &cv);
      tw[tid] = make_float2(cv, sv); }
    __syncthreads();
    const int wave = tid >> 6, lane = tid & 63;
    const int rid = blockIdx.x * 4 + wave;
    const float* tr = tgt + (size_t)rid * WN;
    const float* sr = src + (size_t)rid * WN;
    const int rb6 = (int)(__brev((unsigned)lane) >> 26);   // brev6(lane)
    const int B3[8] = {0,256,128,384,64,320,192,448};      // brev3(j)*64
    cplx v[8];
    #pragma unroll
    for (int j = 0; j < 8; ++j){ int o = B3[j] + rb6; v[j] = make_float2(tr[o], sr[o]); }
    fft512_regs(v, (const float2*)tw, ds + wave * 576, lane);
    cplx* orow = Fz + (size_t)rid * WN;
    #pragma unroll
    for (int j = 0; j < 8; ++j) orow[64*j + lane] = v[j];
}

// ---- merged radix-4 passes for column FFT (stages (1,2),(3,4),(5,6),(7,8) + stage 9)
// op-for-op equal to sequential radix-2 except w2' formed as i*w2 rotation.
__device__ __forceinline__ void col_fft_passes(cplx* sm, const float2* tw, int tid, float sgn){
    #pragma unroll
    for (int pass = 0; pass < 4; ++pass){
        const int st = 2 * pass + 1;
        const int h1 = 1 << (st - 1);
        #pragma unroll
        for (int t2i = 0; t2i < 4; ++t2i){
            int t2 = tid + t2i * 256;            // 1024 quads: 128/col x 8 cols
            int c = t2 & 7, k = t2 >> 3;
            int q = k & (h1 - 1);
            int i0 = ((k >> (st - 1)) << (st + 1)) + q;
            cplx w1 = *(const cplx*)&tw[q << (9 - st)];
            cplx w2 = *(const cplx*)&tw[q << (8 - st)];
            cplx x0 = sm[cswz(i0,        c)];
            cplx x1 = sm[cswz(i0 + h1,   c)];
            cplx x2 = sm[cswz(i0 + 2*h1, c)];
            cplx x3 = sm[cswz(i0 + 3*h1, c)];
            cplx t1 = cmul(w1, x1); cplx a = cadd(x0, t1); cplx b = csub(x0, t1);
            cplx t3 = cmul(w1, x3); cplx cc = cadd(x2, t3); cplx d = csub(x2, t3);
            cplx t2c = cmul(w2, cc);
            cplx A = cadd(a, t2c), C = csub(a, t2c);
            cplx e = cmul(w2, d);
            cplx e2 = make_float2(-sgn * e.y, sgn * e.x);   // (i*sgn) * e
            cplx B = cadd(b, e2), D = csub(b, e2);
            sm[cswz(i0,        c)] = A;
            sm[cswz(i0 + h1,   c)] = B;
            sm[cswz(i0 + 2*h1, c)] = C;
            sm[cswz(i0 + 3*h1, c)] = D;
        }
        __syncthreads();
    }
    // final stage 9: half = 256
    #pragma unroll
    for (int t2i = 0; t2i < 8; ++t2i){
        int t2 = tid + t2i * 256;
        int c = t2 & 7, j = t2 >> 3;
        cplx w = *(const cplx*)&tw[j];
        const int a0 = cswz(j, c), a1 = cswz(j + 256, c);
        cplx a = sm[a0];
        cplx t = cmul(w, sm[a1]);
        sm[a0] = cadd(a, t);
        sm[a1] = csub(a, t);
    }
    __syncthreads();
}

// Column-wise forward FFT of F_z, 8 cols/block, in place. grid (WN/8, BN).
__global__ void col_fft_fwd(cplx* __restrict__ buf){
    const int b  = blockIdx.y;
    const int w0 = blockIdx.x * 8;
    const int tid = threadIdx.x;
    __shared__ cplx sm[4608];
    __shared__ float2 tw[256];
    { float sv, cv; sincosf(-TWO_PI * (float)tid * (1.0f/512.0f), &sv, &cv);
      tw[tid] = make_float2(cv, sv); }
    cplx* base = buf + (size_t)b * HN * WN + w0;
    for (int idx = tid; idx < HN * 8; idx += 256){
        int h = idx >> 3, c = idx & 7;
        sm[cswz(brev9(h), c)] = base[(size_t)h * WN + c];
    }
    __syncthreads();
    col_fft_passes(sm, (const float2*)tw, tid, -1.0f);
    for (int idx = tid; idx < HN * 8; idx += 256){
        int h = idx >> 3, c = idx & 7;
        base[(size_t)h * WN + c] = sm[cswz(h, c)];
    }
}

// Hermitian unpack + cross-power + dual row-wise inverse FFT. Wave-per-row-pair.
// grid (65, BN), block 256. P written in place over Fz; cc rows written out.
__global__ void __launch_bounds__(256) cross_rowinv(cplx* __restrict__ Fz, cplx* __restrict__ cc){
    __shared__ float2 tw[256];
    __shared__ cplx ds[4 * 1184];
    const int tid = threadIdx.x;
    { float sv, cv; sincosf(TWO_PI * (float)tid * (1.0f/512.0f), &sv, &cv);
      tw[tid] = make_float2(cv, sv); }
    __syncthreads();
    const int wave = tid >> 6, lane = tid & 63;
    const int p = blockIdx.x * 4 + wave;
    if (p > 256) return;
    const int b = blockIdx.y;
    const int h1 = p, h2 = (HN - p) & (HN - 1);
    cplx* r1 = Fz + ((size_t)b * HN + h1) * WN;
    cplx* r2 = Fz + ((size_t)b * HN + h2) * WN;
    cplx* A = ds + wave * 1184;
    cplx* B = A + 592;
    #pragma unroll
    for (int u = 0; u < 8; ++u){
        A[lane + 64*u] = r1[lane + 64*u];
        B[lane + 64*u] = r2[lane + 64*u];
    }
    asm volatile("s_waitcnt lgkmcnt(0)" ::: "memory");
    const int rb6 = (int)(__brev((unsigned)lane) >> 26);
    const int B3[8] = {0,256,128,384,64,320,192,448};
    cplx v1[8], v2[8];
    #pragma unroll
    for (int j = 0; j < 8; ++j){
        int w  = B3[j] + rb6;
        int wm = (WN - w) & (WN - 1);
        cplx Aw = A[w], Bw = B[w], Am = A[wm], Bm = B[wm];
        // P(k) = -i*(X - conj(Y))*conj(X + conj(Y))/4
        { cplx Bc = make_float2(Bm.x, -Bm.y);
          cplx s = cadd(Aw, Bc);
          cplx d = make_float2(Aw.x - Bc.x, Aw.y - Bc.y);
          cplx D = make_float2(d.x*s.x + d.y*s.y, d.y*s.x - d.x*s.y);
          v1[j] = make_float2(0.25f * D.y, -0.25f * D.x); }
        { cplx Ac = make_float2(Am.x, -Am.y);
          cplx s = cadd(Bw, Ac);
          cplx d = make_float2(Bw.x - Ac.x, Bw.y - Ac.y);
          cplx D = make_float2(d.x*s.x + d.y*s.y, d.y*s.x - d.x*s.y);
          v2[j] = make_float2(0.25f * D.y, -0.25f * D.x); }
        r1[w] = v1[j];   // P writeback (rows owned exclusively by this wave)
        r2[w] = v2[j];
    }
    // v1/v2 are already in phase-1 register order (index brev9(8*lane+j))
    fft512_regs(v1, (const float2*)tw, A, lane);
    fft512_regs(v2, (const float2*)tw, B, lane);
    cplx* c1 = cc + ((size_t)b * HN + h1) * WN;
    cplx* c2 = cc + ((size_t)b * HN + h2) * WN;
    #pragma unroll
    for (int j = 0; j < 8; ++j){ c1[64*j + lane] = v1[j]; c2[64*j + lane] = v2[j]; }
}

// Column-wise inverse FFT + per-block argmax of |cc|^2 (no global writeback).
// grid (WN/8, BN), block 256. cand[b*64+bx] = (maxval, bitcast idx).
__global__ void colinv_argmax(const cplx* __restrict__ buf, float2* __restrict__ cand){
    const int b  = blockIdx.y;
    const int w0 = blockIdx.x * 8;
    const int tid = threadIdx.x;
    __shared__ cplx sm[4608];
    __shared__ float2 tw[256];
    { float sv, cv; sincosf(TWO_PI * (float)tid * (1.0f/512.0f), &sv, &cv);
      tw[tid] = make_float2(cv, sv); }
    const cplx* base = buf + (size_t)b * HN * WN + w0;
    for (int idx = tid; idx < HN * 8; idx += 256){
        int h = idx >> 3, c = idx & 7;
        sm[cswz(brev9(h), c)] = base[(size_t)h * WN + c];
    }
    __syncthreads();
    col_fft_passes(sm, (const float2*)tw, tid, 1.0f);
    float best = -1.0f; int bidx = 0x7fffffff;
    for (int idx = tid; idx < HN * 8; idx += 256){
        int h = idx >> 3, c = idx & 7;
        cplx v = sm[cswz(h, c)];
        float mm = v.x * v.x + v.y * v.y;
        if (mm > best){ best = mm; bidx = h * WN + w0 + c; }
    }
    __shared__ float vals[256];
    __shared__ int   idxs[256];
    vals[tid] = best; idxs[tid] = bidx;
    __syncthreads();
    for (int s = 128; s > 0; s >>= 1){
        if (tid < s){
            if (vals[tid + s] > vals[tid] ||
                (vals[tid + s] == vals[tid] && idxs[tid + s] < idxs[tid])){
                vals[tid] = vals[tid + s]; idxs[tid] = idxs[tid + s];
            }
        }
        __syncthreads();
    }
    if (tid == 0) cand[b * 64 + blockIdx.x] = make_float2(vals[0], __int_as_float(idxs[0]));
}

// Reduce 64 candidates per batch -> coarse shifts + upsample offsets. grid BN, block 64.
__global__ void coarse_reduce(const float2* __restrict__ cand, float* __restrict__ small){
    const int b = blockIdx.x, t = threadIdx.x;
    float2 c = cand[b * 64 + t];
    float v = c.x; int ix = __float_as_int(c.y);
    for (int off = 32; off > 0; off >>= 1){
        float v2 = __shfl_down(v, off);
        int   i2 = __shfl_down(ix, off);
        if (v2 > v || (v2 == v && i2 < ix)){ v = v2; ix = i2; }
    }
    if (t == 0){
        int row = ix / WN, col = ix % WN;
        float sr = (row > HN / 2) ? (float)(row - HN) : (float)row;
        float sc = (col > WN / 2) ? (float)(col - WN) : (float)col;
        small[b * 4 + 0] = sr;
        small[b * 4 + 1] = sc;
        small[b * 4 + 2] = DFTSHIFT - sr * UFV;
        small[b * 4 + 3] = DFTSHIFT - sc * UFV;
    }
}

// Partial T: Tpart[hs][b][r][w] = sum_{h in chunk hs} rk[r][h] * conj(P[b][h][w]).
// grid (WN/64, BN, HS) = 2048 blocks, block 256 = 8 r-groups x 32 w-pairs.
// r padded to 32 (branch-free accumulate); stores guard r < 30.
__global__ void __launch_bounds__(256, 4) upsample_T(const cplx* __restrict__ P,
                                                     const float* __restrict__ small,
                                                     cplx* __restrict__ Tpart){
    const int b = blockIdx.y, hs = blockIdx.z;
    const int tid = threadIdx.x;
    const int wp = tid & 31;              // w-pair
    const int rbase = tid >> 5;           // 0..7, 4 r each (r = rbase*4+u, 0..31)
    const int w = blockIdx.x * 64 + wp * 2;
    const int h0 = hs * HCH;
    const float off0 = small[b * 4 + 2];
    const float CC = TWO_PI / (HN * UFV);
    __shared__ float2 rk[RPAD][HCH];      // 16 KB
    for (int idx = tid; idx < RPAD * HCH; idx += 256){
        int r = idx >> 6, hh = idx & (HCH - 1);
        int h = h0 + hh;
        float fr = (h < HN / 2) ? (float)h : (float)(h - HN);
        float sv, cv; sincosf(-CC * ((float)r - off0) * fr, &sv, &cv);
        rk[r][hh] = make_float2(cv, sv);
    }
    __syncthreads();
    cplx a0[4], a1[4];
    #pragma unroll
    for (int u = 0; u < 4; ++u){ a0[u] = make_float2(0.f,0.f); a1[u] = make_float2(0.f,0.f); }
    const cplx* pc = P + ((size_t)b * HN + h0) * WN + w;
    for (int hh = 0; hh < HCH; hh += 8){
        float4 pv[8];
        #pragma unroll
        for (int k = 0; k < 8; ++k)
            pv[k] = *(const float4*)(pc + (size_t)(hh + k) * WN);
        #pragma unroll
        for (int k = 0; k < 8; ++k){
            #pragma unroll
            for (int u = 0; u < 4; ++u){
                cplx wv = rk[rbase * 4 + u][hh + k];
                // acc += wv * conj(p); conj folded into FMA signs
                a0[u].x += wv.x * pv[k].x + wv.y * pv[k].y;
                a0[u].y += wv.y * pv[k].x - wv.x * pv[k].y;
                a1[u].x += wv.x * pv[k].z + wv.y * pv[k].w;
                a1[u].y += wv.y * pv[k].z - wv.x * pv[k].w;
            }
        }
    }
    #pragma unroll
    for (int u = 0; u < 4; ++u){
        int r = rbase * 4 + u;
        if (r < REGION){
            float4* dst = (float4*)(Tpart + (((size_t)hs * BN + b) * REGION + r) * WN + w);
            *dst = make_float4(a0[u].x, a0[u].y, a1[u].x, a1[u].y);
        }
    }
}

// Partial U: Upart[ws][b][o] = sum_{w in chunk ws} T[b][r][w] * ck[w][c], o = r*30+c.
// T summed on the fly from the HS Tpart partials. grid (WS, BN), block 256.
__global__ void upsample_U_part(const cplx* __restrict__ Tpart, const float* __restrict__ small,
                                cplx* __restrict__ Upart){
    const int ws = blockIdx.x, b = blockIdx.y;
    const int tid = threadIdx.x;
    const int w0 = ws * WCH;
    const float off1 = small[b * 4 + 3];
    const float CC = TWO_PI / (WN * UFV);
    __shared__ float2 Ts[REGION][WCH];
    __shared__ float2 ck[WCH][REGION];
    const size_t TS = (size_t)BN * REGION * WN;
    for (int idx = tid; idx < REGION * WCH; idx += 256){
        int r = idx >> 6, ww = idx & (WCH - 1);
        cplx s = make_float2(0.f, 0.f);
        #pragma unroll
        for (int hs = 0; hs < HS; ++hs)
            s = cadd(s, Tpart[(size_t)hs * TS + ((size_t)b * REGION + r) * WN + w0 + ww]);
        Ts[r][ww] = s;
    }
    for (int idx = tid; idx < WCH * REGION; idx += 256){
        int ww = idx / REGION, c = idx - ww * REGION;
        int w = w0 + ww;
        float fw = (w < WN / 2) ? (float)w : (float)(w - WN);
        float sv, cv; sincosf(-CC * fw * ((float)c - off1), &sv, &cv);
        ck[ww][c] = make_float2(cv, sv);
    }
    __syncthreads();
    #pragma unroll
    for (int q = 0; q < 4; ++q){
        int o = tid + 256 * q;
        if (o < REGION * REGION){
            int r = o / REGION, c = o - r * REGION;
            cplx acc = make_float2(0.f, 0.f);
            #pragma unroll
            for (int ww = 0; ww < WCH; ++ww)
                acc = cadd(acc, cmul(Ts[r][ww], ck[ww][c]));
            Upart[((size_t)ws * BN + b) * (REGION * REGION) + o] = acc;
        }
    }
}

// Sum the WS U-partials, argmax |U|^2, final shifts. grid (BN), block 256.
__global__ void upsample_argmax(const cplx* __restrict__ Upart, const float* __restrict__ small,
                                float* __restrict__ out){
    const int b = blockIdx.x;
    const int tid = threadIdx.x;
    float best = -1.0f; int bidx = 0x7fffffff;
    #pragma unroll
    for (int q = 0; q < 4; ++q){
        int o = tid + 256 * q;
        if (o < REGION * REGION){
            cplx u = make_float2(0.f, 0.f);
            #pragma unroll
            for (int ws = 0; ws < WS; ++ws)
                u = cadd(u, Upart[((size_t)ws * BN + b) * (REGION * REGION) + o]);
            float m = u.x * u.x + u.y * u.y;
            if (m > best){ best = m; bidx = o; }
        }
    }
    __shared__ float vals[256];
    __shared__ int   idxs[256];
    vals[tid] = best; idxs[tid] = bidx;
    __syncthreads();
    for (int s = 128; s > 0; s >>= 1){
        if (tid < s){
            if (vals[tid + s] > vals[tid] ||
                (vals[tid + s] == vals[tid] && idxs[tid + s] < idxs[tid])){
                vals[tid] = vals[tid + s]; idxs[tid] = idxs[tid + s];
            }
        }
        __syncthreads();
    }
    if (tid == 0){
        int o = idxs[0];
        float r = (float)(o / REGION) - DFTSHIFT;
        float c = (float)(o % REGION) - DFTSHIFT;
        out[b * 2 + 0] = small[b * 4 + 0] + r / UFV;
        out[b * 2 + 1] = small[b * 4 + 1] + c / UFV;
    }
}

extern "C" void kernel_launch(void* const* d_in, const int* in_sizes, int n_in,
                              void* d_out, int out_size, void* d_ws, size_t ws_size,
                              hipStream_t stream){
    const float* tgt = (const float*)d_in[0];
    const float* src = (const float*)d_in[1];
    float* out = (float*)d_out;

    const size_t BIG = (size_t)BN * HN * WN;      // 8,388,608 complex = 67 MB
    cplx* buf1 = (cplx*)d_ws;                     // F_z -> P (image_product)
    cplx* buf2 = buf1 + BIG;                      // cc rows -> Tpart / Upart
    float* small = (float*)(buf2 + BIG);
    float2* cand = (float2*)(small + 128);

    const size_t TSTRIDE = (size_t)BN * REGION * WN;
    cplx* Tpart = buf2;                                // HS * TSTRIDE = 31.5 MB
    cplx* Upart = buf2 + HS * TSTRIDE;                 // WS*BN*900 = 1.8 MB

    dim3 blk(256);
    row_fft_pack<<<dim3(BN * HN / 4), blk, 0, stream>>>(tgt, src, buf1);
    col_fft_fwd<<<dim3(WN / 8, BN), blk, 0, stream>>>(buf1);
    cross_rowinv<<<dim3((257 + 3) / 4, BN), blk, 0, stream>>>(buf1, buf2);
    colinv_argmax<<<dim3(WN / 8, BN), blk, 0, stream>>>(buf2, cand);
    coarse_reduce<<<dim3(BN), dim3(64), 0, stream>>>(cand, small);
    upsample_T<<<dim3(WN / 64, BN, HS), blk, 0, stream>>>(buf1, small, Tpart);
    upsample_U_part<<<dim3(WS, BN), blk, 0, stream>>>(Tpart, small, Upart);
    upsample_argmax<<<dim3(BN), blk, 0, stream>>>(Upart, small, out);
}